// Round 10
// baseline (446.547 us; speedup 1.0000x reference)
//
#include <hip/hip_runtime.h>
#include <math.h>

// Problem constants
// B=2, T=8, H=64, W=64, C=192, WIN=(4,8,8), SHIFT=(2,4,4), HEADS=6, d=32
// N=256 tokens/window, nW=128 windows/batch, B_=256 windows total, HID=768

typedef short short8 __attribute__((ext_vector_type(8)));
typedef short short4v __attribute__((ext_vector_type(4)));
typedef float f32x4 __attribute__((ext_vector_type(4)));

__device__ __forceinline__ short f2bf(float f) {
    union { float f; unsigned u; } v; v.f = f;
    unsigned r = v.u + 0x7FFF + ((v.u >> 16) & 1);  // RNE
    return (short)(r >> 16);
}
__device__ __forceinline__ unsigned pk2bf(float lo, float hi) {
    return ((unsigned)(unsigned short)f2bf(lo)) | (((unsigned)(unsigned short)f2bf(hi)) << 16);
}
__device__ __forceinline__ short f2h(float f) {
    _Float16 h = (_Float16)f;
    union { _Float16 h; short s; } u; u.h = h; return u.s;
}
__device__ __forceinline__ float h2f(short s) {
    union { _Float16 h; short s; } u; u.s = s; return (float)u.h;
}

// tanh-form GELU reduced to sigmoid: x * sigmoid(1.5957691*x*(1+0.044715*x^2))
__device__ __forceinline__ float gelu_fast(float x) {
    float s = x * x;
    float t = fmaf(0.044715f, s, 1.0f);
    float y = -1.5957691216057308f * x * t;
    return x * __builtin_amdgcn_rcpf(1.0f + __expf(y));
}

// ---------------------------------------------------------------- K0: fused setup — 4 weight packs + CPB table in ONE launch
__device__ __forceinline__ void pack_w_dev(const float* __restrict__ w,
                                           short* __restrict__ dst, int K, int bid,
                                           int lane) {
    int ktn = K >> 5;
    int nt = bid / ktn, kt = bid % ktn;
    int r = lane & 15, q = lane >> 4;
    const float* src = w + (size_t)(nt * 16 + r) * K + kt * 32 + q * 8;
    short8 v;
#pragma unroll
    for (int j = 0; j < 8; j++) v[j] = f2bf(src[j]);
    ((short8*)dst)[(size_t)bid * 64 + lane] = v;
}

__global__ __launch_bounds__(64) void setup_k(const float* __restrict__ fc1_w, short* __restrict__ w1p,
                                              const float* __restrict__ fc2_w, short* __restrict__ w2p,
                                              const float* __restrict__ qkv_w, short* __restrict__ wqp,
                                              const float* __restrict__ proj_w, short* __restrict__ wpp,
                                              const float* __restrict__ cw1, const float* __restrict__ cb1,
                                              const float* __restrict__ cw2, float* __restrict__ tbl6) {
    int bid = blockIdx.x;
    int lane = threadIdx.x;
    if (bid < 288) { pack_w_dev(fc1_w, w1p, 192, bid, lane); return; }
    if (bid < 576) { pack_w_dev(fc2_w, w2p, 768, bid - 288, lane); return; }
    if (bid < 792) { pack_w_dev(qkv_w, wqp, 192, bid - 576, lane); return; }
    if (bid < 864) { pack_w_dev(proj_w, wpp, 192, bid - 792, lane); return; }
    int m = bid - 864;
    int it = m / 225;
    int ih = (m / 15) % 15;
    int iw = m % 15;
    float r0 = (float)(it - 3) * (8.0f / 3.0f);
    float r1 = (float)(ih - 7) * (8.0f / 7.0f);
    float r2 = (float)(iw - 7) * (8.0f / 7.0f);
    float c0 = (r0 < 0.f ? -1.f : 1.f) * log2f(fabsf(r0) + 1.0f) * (1.0f / 3.0f);
    float c1 = (r1 < 0.f ? -1.f : 1.f) * log2f(fabsf(r1) + 1.0f) * (1.0f / 3.0f);
    float c2 = (r2 < 0.f ? -1.f : 1.f) * log2f(fabsf(r2) + 1.0f) * (1.0f / 3.0f);
    float hv[8];
#pragma unroll
    for (int j = 0; j < 8; j++) {
        int t = lane * 8 + j;
        hv[j] = fmaxf(0.0f, c0 * cw1[3 * t] + c1 * cw1[3 * t + 1] + c2 * cw1[3 * t + 2] + cb1[t]);
    }
#pragma unroll
    for (int head = 0; head < 6; head++) {
        float s = 0.f;
#pragma unroll
        for (int j = 0; j < 8; j++) s += hv[j] * cw2[head * 512 + lane * 8 + j];
        s += __shfl_xor(s, 1);
        s += __shfl_xor(s, 2);
        s += __shfl_xor(s, 4);
        s += __shfl_xor(s, 8);
        s += __shfl_xor(s, 16);
        s += __shfl_xor(s, 32);
        if (lane == 0) tbl6[m * 6 + head] = s;
    }
}

// ---------------------------------------------------------------- K1b: packed fp16 bias (query-major for swapped-S attn)
// biasQK[h][query(256)][s(8)][key_lo(16)][kh(2)] fp16, key = s*32 + kh*16 + key_lo.
__global__ __launch_bounds__(256) void bias_k(const float* __restrict__ tbl6,
                                              short* __restrict__ biasQK) {
    int idx = blockIdx.x * 256 + threadIdx.x;
    int kh = idx & 1;
    int key_lo = (idx >> 1) & 15;
    int s = (idx >> 5) & 7;
    int query = (idx >> 8) & 255;
    int h = idx >> 16;
    int key = s * 32 + kh * 16 + key_lo;
    int dt = (query >> 6) - (key >> 6) + 3;
    int dh = ((query >> 3) & 7) - ((key >> 3) & 7) + 7;
    int dw = (query & 7) - (key & 7) + 7;
    int rel = dt * 225 + dh * 15 + dw;
    float v = tbl6[rel * 6 + h];
    biasQK[idx] = f2h(16.0f / (1.0f + expf(-v)));
}

// ---------------------------------------------------------------- K2: QKV — registers-only normalize, NO LDS (R9, verified)
__global__ __launch_bounds__(256) void qkv_mfma_k(const float* __restrict__ x,
                                                  const short* __restrict__ wqp,
                                                  const float* __restrict__ qkv_b,
                                                  short* __restrict__ qbf,
                                                  short* __restrict__ kbf,
                                                  short* __restrict__ vtb) {
    int tid = threadIdx.x, lane = tid & 63, w = tid >> 6;
    int r = lane & 15, q = lane >> 4;
    int b_ = blockIdx.x >> 3, n0 = (blockIdx.x & 7) << 5;
    int b = b_ >> 7, win = b_ & 127;
    int wt = win >> 6, wh = (win >> 3) & 7, ww = win & 7;

    short8 af[2][6];
#pragma unroll
    for (int m = 0; m < 2; m++) {
        int n = n0 + m * 16 + r;
        int t0 = ((wt * 4 + (n >> 6)) + 2) & 7;
        int h0 = ((wh * 8 + ((n >> 3) & 7)) + 4) & 63;
        int w0 = ((ww * 8 + (n & 7)) + 4) & 63;
        const float* src = x + ((size_t)((b * 8 + t0) * 64 + h0) * 64 + w0) * 192 + q * 8;
#pragma unroll
        for (int kt = 0; kt < 6; kt++) {
            float4 x0 = *(const float4*)(src + kt * 32);
            float4 x1 = *(const float4*)(src + kt * 32 + 4);
            short8 v;
            v[0] = f2bf(x0.x); v[1] = f2bf(x0.y); v[2] = f2bf(x0.z); v[3] = f2bf(x0.w);
            v[4] = f2bf(x1.x); v[5] = f2bf(x1.y); v[6] = f2bf(x1.z); v[7] = f2bf(x1.w);
            af[m][kt] = v;
        }
    }

    // ---- q/k: 3 nt-pairs per wave, swapped operands, in-register normalize
#pragma unroll
    for (int jj = 0; jj < 3; jj++) {
        int j = w * 3 + jj;                 // pair 0..11: j<6 -> q head j, else k head j-6
        int nt0 = 2 * j, nt1 = 2 * j + 1;
        f32x4 bi0 = *(const f32x4*)(qkv_b + nt0 * 16 + q * 4);
        f32x4 bi1 = *(const f32x4*)(qkv_b + nt1 * 16 + q * 4);
        f32x4 a00 = bi0, a01 = bi0;
        f32x4 a10 = bi1, a11 = bi1;
#pragma unroll
        for (int kt = 0; kt < 6; kt++) {
            short8 b0 = ((const short8*)wqp)[(size_t)(nt0 * 6 + kt) * 64 + lane];
            short8 b1 = ((const short8*)wqp)[(size_t)(nt1 * 6 + kt) * 64 + lane];
            a00 = __builtin_amdgcn_mfma_f32_16x16x32_bf16(b0, af[0][kt], a00, 0, 0, 0);
            a01 = __builtin_amdgcn_mfma_f32_16x16x32_bf16(b0, af[1][kt], a01, 0, 0, 0);
            a10 = __builtin_amdgcn_mfma_f32_16x16x32_bf16(b1, af[0][kt], a10, 0, 0, 0);
            a11 = __builtin_amdgcn_mfma_f32_16x16x32_bf16(b1, af[1][kt], a11, 0, 0, 0);
        }
        float s0 = 0.f, s1 = 0.f;
#pragma unroll
        for (int reg = 0; reg < 4; reg++) {
            s0 += a00[reg] * a00[reg] + a10[reg] * a10[reg];
            s1 += a01[reg] * a01[reg] + a11[reg] * a11[reg];
        }
        s0 += __shfl_xor(s0, 16); s0 += __shfl_xor(s0, 32);
        s1 += __shfl_xor(s1, 16); s1 += __shfl_xor(s1, 32);
        float inv0 = 1.0f / fmaxf(sqrtf(s0), 1e-12f);
        float inv1 = 1.0f / fmaxf(sqrtf(s1), 1e-12f);
        int isq = j < 6;
        int h = isq ? j : j - 6;
        short* dst = (isq ? qbf : kbf) + (size_t)(b_ * 6 + h) * 8192;
        short4v v00, v10, v01, v11;
#pragma unroll
        for (int reg = 0; reg < 4; reg++) {
            v00[reg] = f2bf(a00[reg] * inv0);
            v10[reg] = f2bf(a10[reg] * inv0);
            v01[reg] = f2bf(a01[reg] * inv1);
            v11[reg] = f2bf(a11[reg] * inv1);
        }
        *(short4v*)(dst + (n0 + r) * 32 + q * 4) = v00;
        *(short4v*)(dst + (n0 + r) * 32 + 16 + q * 4) = v10;
        *(short4v*)(dst + (n0 + 16 + r) * 32 + q * 4) = v01;
        *(short4v*)(dst + (n0 + 16 + r) * 32 + 16 + q * 4) = v11;
    }

    // ---- v: 3 tiles per wave, unswapped, transposed bf16 out
#pragma unroll
    for (int jj = 0; jj < 3; jj++) {
        int nt = 24 + w * 3 + jj;
        float bias = qkv_b[nt * 16 + r];
        f32x4 a0 = {bias, bias, bias, bias};
        f32x4 a1 = {bias, bias, bias, bias};
#pragma unroll
        for (int kt = 0; kt < 6; kt++) {
            short8 bfr = ((const short8*)wqp)[(size_t)(nt * 6 + kt) * 64 + lane];
            a0 = __builtin_amdgcn_mfma_f32_16x16x32_bf16(af[0][kt], bfr, a0, 0, 0, 0);
            a1 = __builtin_amdgcn_mfma_f32_16x16x32_bf16(af[1][kt], bfr, a1, 0, 0, 0);
        }
        int ch = nt * 16 + r - 384;
        int hh = ch >> 5, dd = ch & 31;
        short* vb = vtb + ((size_t)(b_ * 6 + hh) * 32 + dd) * 256 + n0;
        short4v p0, p1;
#pragma unroll
        for (int reg = 0; reg < 4; reg++) { p0[reg] = f2bf(a0[reg]); p1[reg] = f2bf(a1[reg]); }
        *(short4v*)(vb + q * 4) = p0;
        *(short4v*)(vb + 16 + q * 4) = p1;
    }
}

// ---------------------------------------------------------------- K3: flash attention, SWAPPED-S form (R8, verified)
#define KSTR 40
#define VSTR 264
__global__ __launch_bounds__(256) void attn_mfma_k(const short* __restrict__ qbf,
                                                   const short* __restrict__ kbf,
                                                   const short* __restrict__ vtb,
                                                   const short* __restrict__ biasQK,
                                                   const float* __restrict__ logit_scale,
                                                   short* __restrict__ att) {
    __shared__ short Ks[256 * KSTR];      // 20480 B
    __shared__ short Vs[32 * VSTR];       // 16896 B
    int tid = threadIdx.x, lane = tid & 63, w = tid >> 6;
    int r = lane & 15, q = lane >> 4;
    int b_ = blockIdx.x / 6, h = blockIdx.x % 6;
    size_t base = (size_t)(b_ * 6 + h) * 8192;

    const short8* kg = (const short8*)(kbf + base);
    const short8* vg = (const short8*)(vtb + base);
    for (int i = tid; i < 1024; i += 256) {
        short8 kv = kg[i];
        *(short8*)&Ks[(i >> 2) * KSTR + (i & 3) * 8] = kv;
        short8 vv = vg[i];
        *(short8*)&Vs[(i >> 5) * VSTR + (i & 31) * 8] = vv;
    }

    short8 qf[4];
#pragma unroll
    for (int mt = 0; mt < 4; mt++)
        qf[mt] = *(const short8*)(qbf + base + (size_t)(w * 64 + mt * 16 + r) * 32 + q * 8);

    float scale = __expf(fminf(logit_scale[h], 4.6051702f));
    float M = scale + 16.0f;
    int win = b_ & 127;
    int wt4 = (win >> 6) * 4, wh8 = ((win >> 3) & 7) * 8, ww8 = (win & 7) * 8;
    auto region = [&](int n) {
        int ts = wt4 + (n >> 6), hs = wh8 + ((n >> 3) & 7), wsv = ww8 + (n & 7);
        int rt = ts < 4 ? 0 : (ts < 6 ? 1 : 2);
        int rh = hs < 56 ? 0 : (hs < 60 ? 1 : 2);
        int rw = wsv < 56 ? 0 : (wsv < 60 ? 1 : 2);
        return rt * 9 + rh * 3 + rw;
    };
    int qreg[4];
#pragma unroll
    for (int mt = 0; mt < 4; mt++) qreg[mt] = region(w * 64 + mt * 16 + r);
    int rw4[4];
#pragma unroll
    for (int reg = 0; reg < 4; reg++) {
        int wsv = ww8 + (q & 1) * 4 + reg;
        rw4[reg] = wsv < 56 ? 0 : (wsv < 60 ? 1 : 2);
    }

    f32x4 O[4][2];
    float lpv[4];
#pragma unroll
    for (int mt = 0; mt < 4; mt++) {
        O[mt][0] = (f32x4){0.f, 0.f, 0.f, 0.f};
        O[mt][1] = (f32x4){0.f, 0.f, 0.f, 0.f};
        lpv[mt] = 0.f;
    }
    __syncthreads();

    int qa = 2 * (q & 1);
    int srcA = (qa << 4) | r;
    int srcB = ((qa + 1) << 4) | r;
    bool loSel = q < 2;

    const short* bh = biasQK + ((size_t)h << 16);
    for (int s = 0; s < 8; s++) {
        short8 kf0 = *(const short8*)&Ks[(s * 32 + r) * KSTR + q * 8];
        short8 kf1 = *(const short8*)&Ks[(s * 32 + 16 + r) * KSTR + q * 8];
        short8 vf0 = *(const short8*)&Vs[r * VSTR + s * 32 + q * 8];
        short8 vf1 = *(const short8*)&Vs[(16 + r) * VSTR + s * 32 + q * 8];
        int ts = wt4 + (s >> 1);
        int rt_s = (ts < 4 ? 0 : (ts < 6 ? 1 : 2)) * 9;
        int hs0 = wh8 + (s & 1) * 4 + (q >> 1);
        int hs1 = hs0 + 2;
        int rh0 = (hs0 < 56 ? 0 : (hs0 < 60 ? 1 : 2)) * 3;
        int rh1 = (hs1 < 56 ? 0 : (hs1 < 60 ? 1 : 2)) * 3;
        int kreg0[4], kreg1[4];
#pragma unroll
        for (int reg = 0; reg < 4; reg++) {
            kreg0[reg] = rt_s + rh0 + rw4[reg];
            kreg1[reg] = rt_s + rh1 + rw4[reg];
        }
#pragma unroll
        for (int mt = 0; mt < 4; mt++) {
            f32x4 s0 = {0.f, 0.f, 0.f, 0.f};
            f32x4 s1 = {0.f, 0.f, 0.f, 0.f};
            s0 = __builtin_amdgcn_mfma_f32_16x16x32_bf16(kf0, qf[mt], s0, 0, 0, 0);
            s1 = __builtin_amdgcn_mfma_f32_16x16x32_bf16(kf1, qf[mt], s1, 0, 0, 0);
            int query = w * 64 + mt * 16 + r;
            short8 bv = *(const short8*)(bh + (size_t)query * 256 + s * 32 + q * 8);
            float p0[4], p1[4];
            float lsum = 0.f;
#pragma unroll
            for (int reg = 0; reg < 4; reg++) {
                float bb0 = h2f(bv[2 * reg]);
                float bb1 = h2f(bv[2 * reg + 1]);
                float v0 = s0[reg] * scale + bb0 + (kreg0[reg] == qreg[mt] ? 0.f : -100.f) - M;
                float v1 = s1[reg] * scale + bb1 + (kreg1[reg] == qreg[mt] ? 0.f : -100.f) - M;
                p0[reg] = __expf(v0);
                p1[reg] = __expf(v1);
                lsum += p0[reg] + p1[reg];
            }
            lpv[mt] += lsum;
            unsigned lo0 = pk2bf(p0[0], p0[1]);
            unsigned lo1 = pk2bf(p0[2], p0[3]);
            unsigned hi0 = pk2bf(p1[0], p1[1]);
            unsigned hi1 = pk2bf(p1[2], p1[3]);
            unsigned a0 = __shfl((int)lo0, srcA);
            unsigned a1 = __shfl((int)lo1, srcA);
            unsigned a2 = __shfl((int)lo0, srcB);
            unsigned a3 = __shfl((int)lo1, srcB);
            unsigned b0 = __shfl((int)hi0, srcA);
            unsigned b1 = __shfl((int)hi1, srcA);
            unsigned b2 = __shfl((int)hi0, srcB);
            unsigned b3 = __shfl((int)hi1, srcB);
            union { unsigned u[4]; short8 s8; } pu;
            pu.u[0] = loSel ? a0 : b0;
            pu.u[1] = loSel ? a1 : b1;
            pu.u[2] = loSel ? a2 : b2;
            pu.u[3] = loSel ? a3 : b3;
            short8 pb = pu.s8;
            O[mt][0] = __builtin_amdgcn_mfma_f32_16x16x32_bf16(vf0, pb, O[mt][0], 0, 0, 0);
            O[mt][1] = __builtin_amdgcn_mfma_f32_16x16x32_bf16(vf1, pb, O[mt][1], 0, 0, 0);
        }
    }

#pragma unroll
    for (int mt = 0; mt < 4; mt++) {
        float v = lpv[mt];
        v += __shfl_xor(v, 16);
        v += __shfl_xor(v, 32);
        lpv[mt] = 1.0f / v;
    }
#pragma unroll
    for (int mt = 0; mt < 4; mt++) {
        float linv = lpv[mt];
        int query = w * 64 + mt * 16 + r;
        short* dst = att + ((size_t)b_ * 256 + query) * 192 + h * 32 + q * 4;
#pragma unroll
        for (int nt = 0; nt < 2; nt++) {
            short4v pv;
#pragma unroll
            for (int reg = 0; reg < 4; reg++) pv[reg] = f2bf(O[mt][nt][reg] * linv);
            *(short4v*)(dst + nt * 16) = pv;
        }
    }
}

// ---------------------------------------------------------------- K4: out-proj via bf16 MFMA (swapped operands) + LN + roll-scatter + residual
__global__ __launch_bounds__(256) void proj_mfma_k(const short* __restrict__ att,
                                                   const short* __restrict__ wpp,
                                                   const float* __restrict__ proj_b,
                                                   const float* __restrict__ x,
                                                   const float* __restrict__ g1,
                                                   const float* __restrict__ b1n,
                                                   float* __restrict__ out,
                                                   short* __restrict__ xmb) {
    __shared__ float ps[32][4], pss[32][4];
    __shared__ float mean_s[32], inv_s[32];
    int tid = threadIdx.x, lane = tid & 63, w = tid >> 6;
    int r = lane & 15, q = lane >> 4;
    int b_ = blockIdx.x >> 3, n0 = (blockIdx.x & 7) << 5;

    short8 af[2][6];
#pragma unroll
    for (int m = 0; m < 2; m++) {
        const short* src = att + ((size_t)b_ * 256 + n0 + m * 16 + r) * 192 + q * 8;
#pragma unroll
        for (int kt = 0; kt < 6; kt++)
            af[m][kt] = *(const short8*)(src + kt * 32);
    }
    f32x4 acc[3][2];
#pragma unroll
    for (int ntl = 0; ntl < 3; ntl++) {
        int nt = w * 3 + ntl;
        f32x4 binit = *(const f32x4*)(proj_b + nt * 16 + q * 4);
        short8 bfr[6];
#pragma unroll
        for (int kt = 0; kt < 6; kt++)
            bfr[kt] = ((const short8*)wpp)[(size_t)(nt * 6 + kt) * 64 + lane];
        f32x4 a0 = binit, a1 = binit;
#pragma unroll
        for (int kt = 0; kt < 6; kt++) {
            a0 = __builtin_amdgcn_mfma_f32_16x16x32_bf16(bfr[kt], af[0][kt], a0, 0, 0, 0);
            a1 = __builtin_amdgcn_mfma_f32_16x16x32_bf16(bfr[kt], af[1][kt], a1, 0, 0, 0);
        }
        acc[ntl][0] = a0;
        acc[ntl][1] = a1;
    }
    float s0 = 0.f, ss0 = 0.f, s1 = 0.f, ss1 = 0.f;
#pragma unroll
    for (int ntl = 0; ntl < 3; ntl++)
#pragma unroll
        for (int reg = 0; reg < 4; reg++) {
            float z0 = acc[ntl][0][reg], z1 = acc[ntl][1][reg];
            s0 += z0; ss0 += z0 * z0;
            s1 += z1; ss1 += z1 * z1;
        }
    s0 += __shfl_xor(s0, 16); ss0 += __shfl_xor(ss0, 16);
    s0 += __shfl_xor(s0, 32); ss0 += __shfl_xor(ss0, 32);
    s1 += __shfl_xor(s1, 16); ss1 += __shfl_xor(ss1, 16);
    s1 += __shfl_xor(s1, 32); ss1 += __shfl_xor(ss1, 32);
    if (q == 0) {
        ps[r][w] = s0;  pss[r][w] = ss0;
        ps[16 + r][w] = s1;  pss[16 + r][w] = ss1;
    }
    __syncthreads();
    if (tid < 32) {
        float sm = ps[tid][0] + ps[tid][1] + ps[tid][2] + ps[tid][3];
        float sq = pss[tid][0] + pss[tid][1] + pss[tid][2] + pss[tid][3];
        float mean = sm * (1.0f / 192.0f);
        float var = sq * (1.0f / 192.0f) - mean * mean;
        mean_s[tid] = mean;
        inv_s[tid] = 1.0f / sqrtf(var + 1e-5f);
    }
    __syncthreads();
    int b = b_ >> 7, win = b_ & 127;
    int wt = win >> 6, wh = (win >> 3) & 7, ww = win & 7;
#pragma unroll
    for (int mh = 0; mh < 2; mh++) {
        int token = mh * 16 + r;
        int n = n0 + token;
        int t0 = ((wt * 4 + (n >> 6)) + 2) & 7;
        int h0 = ((wh * 8 + ((n >> 3) & 7)) + 4) & 63;
        int w0 = ((ww * 8 + (n & 7)) + 4) & 63;
        size_t gb = ((size_t)((b * 8 + t0) * 64 + h0) * 64 + w0) * 192;
        float mean = mean_s[token], inv = inv_s[token];
#pragma unroll
        for (int ntl = 0; ntl < 3; ntl++) {
            int ch = (w * 3 + ntl) * 16 + q * 4;
            f32x4 zv = acc[ntl][mh];
            f32x4 gv = *(const f32x4*)(g1 + ch);
            f32x4 bv = *(const f32x4*)(b1n + ch);
            f32x4 xv = *(const f32x4*)(x + gb + ch);
            f32x4 o;
            short4v xm;
#pragma unroll
            for (int j = 0; j < 4; j++) {
                o[j] = xv[j] + (zv[j] - mean) * inv * gv[j] + bv[j];
                xm[j] = f2bf(o[j]);
            }
            *(f32x4*)(out + gb + ch) = o;
            *(short4v*)(xmb + gb + ch) = xm;
        }
    }
}

// ---------------------------------------------------------------- K5: MLP — NO Xs staging; X frags straight from global (L2-warm)
// R10: R3's "drop Xs" failure was the __launch_bounds__(512,8) VGPR-32 cap
// (spills, 1GB scratch), NOT the concept. At natural VGPR (~56-64, bound 4),
// LDS falls 62KB -> 36.4KB -> 4 blocks/CU; RF allows 8 waves/SIMD -> up to
// 32 waves/CU (was 13). mlp is latency-bound (no pipe >31%) -> TLP is the lever.
// X reads: 16 rows x 64B contiguous per wave-load, L1/L2-resident (proj just
// wrote xmb). Failure signature to watch: VGPR>80 or scratch -> revert.
#define H2STR 264
__global__ __launch_bounds__(512, 4) void mlp_mfma_k(const short* __restrict__ xmb,
                                                     const short* __restrict__ w1p,
                                                     const short* __restrict__ w2p,
                                                     const float* __restrict__ fc1_b,
                                                     const float* __restrict__ fc2_b,
                                                     const float* __restrict__ g2,
                                                     const float* __restrict__ b2,
                                                     float* __restrict__ out) {
    __shared__ short Hs[64 * H2STR];  // 33792 B
    __shared__ float ps[64][4], pss[64][4];
    __shared__ float mean_s[64], inv_s[64];
    int tid = threadIdx.x;
    int lane = tid & 63, w = tid >> 6;
    int r = lane & 15, q = lane >> 4;
    size_t tok0 = (size_t)blockIdx.x * 64;

    int mg = w >> 2;
    int ng = w & 3;
    f32x4 acc2[6];
#pragma unroll
    for (int i = 0; i < 6; i++) acc2[i] = (f32x4){0.f, 0.f, 0.f, 0.f};

    // per-lane base for X fragment loads straight from global
    const short* xbase = xmb + (tok0 + r) * 192 + q * 8;

    for (int c = 0; c < 3; c++) {
        {
            int ntg0 = c * 16 + 2 * w;
            f32x4 a[2][4];
#pragma unroll
            for (int ntl = 0; ntl < 2; ntl++) {
                f32x4 binit = *(const f32x4*)(fc1_b + (ntg0 + ntl) * 16 + q * 4);
#pragma unroll
                for (int m = 0; m < 4; m++) a[ntl][m] = binit;
            }
#pragma unroll
            for (int kt = 0; kt < 6; kt++) {
                short8 w0 = ((const short8*)w1p)[(size_t)((ntg0) * 6 + kt) * 64 + lane];
                short8 w1f = ((const short8*)w1p)[(size_t)((ntg0 + 1) * 6 + kt) * 64 + lane];
                short8 xb[4];
#pragma unroll
                for (int m = 0; m < 4; m++)
                    xb[m] = *(const short8*)(xbase + (size_t)(m * 16) * 192 + kt * 32);
#pragma unroll
                for (int m = 0; m < 4; m++) {
                    a[0][m] = __builtin_amdgcn_mfma_f32_16x16x32_bf16(w0, xb[m], a[0][m], 0, 0, 0);
                    a[1][m] = __builtin_amdgcn_mfma_f32_16x16x32_bf16(w1f, xb[m], a[1][m], 0, 0, 0);
                }
            }
#pragma unroll
            for (int ntl = 0; ntl < 2; ntl++) {
                int hcol = (2 * w + ntl) * 16 + q * 4;
#pragma unroll
                for (int m = 0; m < 4; m++) {
                    short4v p;
#pragma unroll
                    for (int reg = 0; reg < 4; reg++) p[reg] = f2bf(gelu_fast(a[ntl][m][reg]));
                    *(short4v*)&Hs[(m * 16 + r) * H2STR + hcol] = p;
                }
            }
        }
        __syncthreads();

#pragma unroll
        for (int kk = 0; kk < 8; kk++) {
            short8 hb0 = *(const short8*)&Hs[((mg * 2) * 16 + r) * H2STR + kk * 32 + q * 8];
            short8 hb1 = *(const short8*)&Hs[((mg * 2 + 1) * 16 + r) * H2STR + kk * 32 + q * 8];
            int kkg = c * 8 + kk;
#pragma unroll
            for (int n = 0; n < 3; n++) {
                int ntz = ng * 3 + n;
                short8 wf = ((const short8*)w2p)[(size_t)(ntz * 24 + kkg) * 64 + lane];
                acc2[n * 2 + 0] = __builtin_amdgcn_mfma_f32_16x16x32_bf16(wf, hb0, acc2[n * 2 + 0], 0, 0, 0);
                acc2[n * 2 + 1] = __builtin_amdgcn_mfma_f32_16x16x32_bf16(wf, hb1, acc2[n * 2 + 1], 0, 0, 0);
            }
        }
        __syncthreads();
    }

    float s0 = 0.f, ss0 = 0.f, s1 = 0.f, ss1 = 0.f;
#pragma unroll
    for (int n = 0; n < 3; n++) {
        f32x4 b4 = *(const f32x4*)(fc2_b + (ng * 3 + n) * 16 + q * 4);
        f32x4 z0 = acc2[n * 2 + 0] + b4;
        f32x4 z1 = acc2[n * 2 + 1] + b4;
        acc2[n * 2 + 0] = z0;
        acc2[n * 2 + 1] = z1;
#pragma unroll
        for (int reg = 0; reg < 4; reg++) {
            s0 += z0[reg]; ss0 += z0[reg] * z0[reg];
            s1 += z1[reg]; ss1 += z1[reg] * z1[reg];
        }
    }
    s0 += __shfl_xor(s0, 16); ss0 += __shfl_xor(ss0, 16);
    s0 += __shfl_xor(s0, 32); ss0 += __shfl_xor(ss0, 32);
    s1 += __shfl_xor(s1, 16); ss1 += __shfl_xor(ss1, 16);
    s1 += __shfl_xor(s1, 32); ss1 += __shfl_xor(ss1, 32);
    if (q == 0) {
        int t0 = mg * 32 + r;
        ps[t0][ng] = s0;  pss[t0][ng] = ss0;
        ps[t0 + 16][ng] = s1;  pss[t0 + 16][ng] = ss1;
    }
    __syncthreads();
    if (tid < 64) {
        float sm = ps[tid][0] + ps[tid][1] + ps[tid][2] + ps[tid][3];
        float sq = pss[tid][0] + pss[tid][1] + pss[tid][2] + pss[tid][3];
        float mean = sm * (1.0f / 192.0f);
        float var = sq * (1.0f / 192.0f) - mean * mean;
        mean_s[tid] = mean;
        inv_s[tid] = 1.0f / sqrtf(var + 1e-5f);
    }
    __syncthreads();
#pragma unroll
    for (int n = 0; n < 3; n++) {
        int ntz = ng * 3 + n;
        f32x4 g4 = *(const f32x4*)(g2 + ntz * 16 + q * 4);
        f32x4 bb4 = *(const f32x4*)(b2 + ntz * 16 + q * 4);
#pragma unroll
        for (int mh = 0; mh < 2; mh++) {
            int token = mg * 32 + mh * 16 + r;
            float mean = mean_s[token], inv = inv_s[token];
            size_t gi = (tok0 + token) * 192 + ntz * 16 + q * 4;
            f32x4 o = *(const f32x4*)(out + gi);
            f32x4 z = acc2[n * 2 + mh];
            f32x4 res;
#pragma unroll
            for (int reg = 0; reg < 4; reg++)
                res[reg] = o[reg] + (z[reg] - mean) * inv * g4[reg] + bb4[reg];
            *(f32x4*)(out + gi) = res;
        }
    }
}

// ---------------------------------------------------------------- launch
extern "C" void kernel_launch(void* const* d_in, const int* in_sizes, int n_in,
                              void* d_out, int out_size, void* d_ws, size_t ws_size,
                              hipStream_t stream) {
    const float* x           = (const float*)d_in[0];
    const float* qkv_w       = (const float*)d_in[1];
    const float* qkv_b       = (const float*)d_in[2];
    const float* proj_w      = (const float*)d_in[3];
    const float* proj_b      = (const float*)d_in[4];
    const float* cpb_w1      = (const float*)d_in[5];
    const float* cpb_b1      = (const float*)d_in[6];
    const float* cpb_w2      = (const float*)d_in[7];
    const float* logit_scale = (const float*)d_in[8];
    const float* norm1_g     = (const float*)d_in[9];
    const float* norm1_b     = (const float*)d_in[10];
    const float* norm2_g     = (const float*)d_in[11];
    const float* norm2_b     = (const float*)d_in[12];
    const float* fc1_w       = (const float*)d_in[13];
    const float* fc1_b       = (const float*)d_in[14];
    const float* fc2_w       = (const float*)d_in[15];
    const float* fc2_b       = (const float*)d_in[16];
    float* out = (float*)d_out;

    float* ws = (float*)d_ws;
    const size_t QKVE = (size_t)256 * 6 * 256 * 32;   // 12,582,912 elems
    short* att    = (short*)ws;                       // bf16, region kept fp32-sized
    short* biasQK = (short*)(ws + QKVE);              // fp16 packed, 393,216 shorts
    float* tbl6   = ws + QKVE + (size_t)6 * 256 * 256;  // 9,450 fp32
    short* w1pack = (short*)(tbl6 + 9472);
    short* w2pack = w1pack + (size_t)768 * 192;
    short* wqpack = w2pack + (size_t)192 * 768;
    short* wppack = wqpack + (size_t)576 * 192;
    short* qbf    = wppack + (size_t)192 * 192;       // bf16, 12,582,912 each
    short* kbf    = qbf + QKVE;
    short* vtb    = kbf + QKVE;
    short* xmb    = vtb + QKVE;                       // bf16 x_mid, raster order

    hipLaunchKernelGGL(setup_k, dim3(2439), dim3(64), 0, stream,
                       fc1_w, w1pack, fc2_w, w2pack, qkv_w, wqpack, proj_w, wppack,
                       cpb_w1, cpb_b1, cpb_w2, tbl6);
    hipLaunchKernelGGL(bias_k, dim3(1536), dim3(256), 0, stream, tbl6, biasQK);
    hipLaunchKernelGGL(qkv_mfma_k, dim3(2048), dim3(256), 0, stream, x, wqpack, qkv_b, qbf, kbf, vtb);
    hipLaunchKernelGGL(attn_mfma_k, dim3(1536), dim3(256), 0, stream, qbf, kbf, vtb, biasQK, logit_scale, att);
    hipLaunchKernelGGL(proj_mfma_k, dim3(2048), dim3(256), 0, stream, att, wppack, proj_b, x, norm1_g, norm1_b, out, xmb);
    hipLaunchKernelGGL(mlp_mfma_k, dim3(1024), dim3(512), 0, stream, xmb, w1pack, w2pack,
                       fc1_b, fc2_b, norm2_g, norm2_b, out);
}

// Round 11
// 351.760 us; speedup vs baseline: 1.2695x; 1.2695x over previous
//
#include <hip/hip_runtime.h>
#include <math.h>

// Problem constants
// B=2, T=8, H=64, W=64, C=192, WIN=(4,8,8), SHIFT=(2,4,4), HEADS=6, d=32
// N=256 tokens/window, nW=128 windows/batch, B_=256 windows total, HID=768

typedef short short8 __attribute__((ext_vector_type(8)));
typedef short short4v __attribute__((ext_vector_type(4)));
typedef float f32x4 __attribute__((ext_vector_type(4)));

__device__ __forceinline__ short f2bf(float f) {
    union { float f; unsigned u; } v; v.f = f;
    unsigned r = v.u + 0x7FFF + ((v.u >> 16) & 1);  // RNE
    return (short)(r >> 16);
}
__device__ __forceinline__ unsigned pk2bf(float lo, float hi) {
    return ((unsigned)(unsigned short)f2bf(lo)) | (((unsigned)(unsigned short)f2bf(hi)) << 16);
}
__device__ __forceinline__ short f2h(float f) {
    _Float16 h = (_Float16)f;
    union { _Float16 h; short s; } u; u.h = h; return u.s;
}
__device__ __forceinline__ float h2f(short s) {
    union { _Float16 h; short s; } u; u.s = s; return (float)u.h;
}

// tanh-form GELU reduced to sigmoid: x * sigmoid(1.5957691*x*(1+0.044715*x^2))
__device__ __forceinline__ float gelu_fast(float x) {
    float s = x * x;
    float t = fmaf(0.044715f, s, 1.0f);
    float y = -1.5957691216057308f * x * t;
    return x * __builtin_amdgcn_rcpf(1.0f + __expf(y));
}

// ---------------------------------------------------------------- K0: fused setup — 4 weight packs + CPB table in ONE launch
__device__ __forceinline__ void pack_w_dev(const float* __restrict__ w,
                                           short* __restrict__ dst, int K, int bid,
                                           int lane) {
    int ktn = K >> 5;
    int nt = bid / ktn, kt = bid % ktn;
    int r = lane & 15, q = lane >> 4;
    const float* src = w + (size_t)(nt * 16 + r) * K + kt * 32 + q * 8;
    short8 v;
#pragma unroll
    for (int j = 0; j < 8; j++) v[j] = f2bf(src[j]);
    ((short8*)dst)[(size_t)bid * 64 + lane] = v;
}

__global__ __launch_bounds__(64) void setup_k(const float* __restrict__ fc1_w, short* __restrict__ w1p,
                                              const float* __restrict__ fc2_w, short* __restrict__ w2p,
                                              const float* __restrict__ qkv_w, short* __restrict__ wqp,
                                              const float* __restrict__ proj_w, short* __restrict__ wpp,
                                              const float* __restrict__ cw1, const float* __restrict__ cb1,
                                              const float* __restrict__ cw2, float* __restrict__ tbl6) {
    int bid = blockIdx.x;
    int lane = threadIdx.x;
    if (bid < 288) { pack_w_dev(fc1_w, w1p, 192, bid, lane); return; }
    if (bid < 576) { pack_w_dev(fc2_w, w2p, 768, bid - 288, lane); return; }
    if (bid < 792) { pack_w_dev(qkv_w, wqp, 192, bid - 576, lane); return; }
    if (bid < 864) { pack_w_dev(proj_w, wpp, 192, bid - 792, lane); return; }
    int m = bid - 864;
    int it = m / 225;
    int ih = (m / 15) % 15;
    int iw = m % 15;
    float r0 = (float)(it - 3) * (8.0f / 3.0f);
    float r1 = (float)(ih - 7) * (8.0f / 7.0f);
    float r2 = (float)(iw - 7) * (8.0f / 7.0f);
    float c0 = (r0 < 0.f ? -1.f : 1.f) * log2f(fabsf(r0) + 1.0f) * (1.0f / 3.0f);
    float c1 = (r1 < 0.f ? -1.f : 1.f) * log2f(fabsf(r1) + 1.0f) * (1.0f / 3.0f);
    float c2 = (r2 < 0.f ? -1.f : 1.f) * log2f(fabsf(r2) + 1.0f) * (1.0f / 3.0f);
    float hv[8];
#pragma unroll
    for (int j = 0; j < 8; j++) {
        int t = lane * 8 + j;
        hv[j] = fmaxf(0.0f, c0 * cw1[3 * t] + c1 * cw1[3 * t + 1] + c2 * cw1[3 * t + 2] + cb1[t]);
    }
#pragma unroll
    for (int head = 0; head < 6; head++) {
        float s = 0.f;
#pragma unroll
        for (int j = 0; j < 8; j++) s += hv[j] * cw2[head * 512 + lane * 8 + j];
        s += __shfl_xor(s, 1);
        s += __shfl_xor(s, 2);
        s += __shfl_xor(s, 4);
        s += __shfl_xor(s, 8);
        s += __shfl_xor(s, 16);
        s += __shfl_xor(s, 32);
        if (lane == 0) tbl6[m * 6 + head] = s;
    }
}

// ---------------------------------------------------------------- K1b: packed fp16 bias (query-major for swapped-S attn)
// biasQK[h][query(256)][s(8)][key_lo(16)][kh(2)] fp16, key = s*32 + kh*16 + key_lo.
__global__ __launch_bounds__(256) void bias_k(const float* __restrict__ tbl6,
                                              short* __restrict__ biasQK) {
    int idx = blockIdx.x * 256 + threadIdx.x;
    int kh = idx & 1;
    int key_lo = (idx >> 1) & 15;
    int s = (idx >> 5) & 7;
    int query = (idx >> 8) & 255;
    int h = idx >> 16;
    int key = s * 32 + kh * 16 + key_lo;
    int dt = (query >> 6) - (key >> 6) + 3;
    int dh = ((query >> 3) & 7) - ((key >> 3) & 7) + 7;
    int dw = (query & 7) - (key & 7) + 7;
    int rel = dt * 225 + dh * 15 + dw;
    float v = tbl6[rel * 6 + h];
    biasQK[idx] = f2h(16.0f / (1.0f + expf(-v)));
}

// ---------------------------------------------------------------- K2: QKV — registers-only normalize, NO LDS (R9, verified)
__global__ __launch_bounds__(256) void qkv_mfma_k(const float* __restrict__ x,
                                                  const short* __restrict__ wqp,
                                                  const float* __restrict__ qkv_b,
                                                  short* __restrict__ qbf,
                                                  short* __restrict__ kbf,
                                                  short* __restrict__ vtb) {
    int tid = threadIdx.x, lane = tid & 63, w = tid >> 6;
    int r = lane & 15, q = lane >> 4;
    int b_ = blockIdx.x >> 3, n0 = (blockIdx.x & 7) << 5;
    int b = b_ >> 7, win = b_ & 127;
    int wt = win >> 6, wh = (win >> 3) & 7, ww = win & 7;

    short8 af[2][6];
#pragma unroll
    for (int m = 0; m < 2; m++) {
        int n = n0 + m * 16 + r;
        int t0 = ((wt * 4 + (n >> 6)) + 2) & 7;
        int h0 = ((wh * 8 + ((n >> 3) & 7)) + 4) & 63;
        int w0 = ((ww * 8 + (n & 7)) + 4) & 63;
        const float* src = x + ((size_t)((b * 8 + t0) * 64 + h0) * 64 + w0) * 192 + q * 8;
#pragma unroll
        for (int kt = 0; kt < 6; kt++) {
            float4 x0 = *(const float4*)(src + kt * 32);
            float4 x1 = *(const float4*)(src + kt * 32 + 4);
            short8 v;
            v[0] = f2bf(x0.x); v[1] = f2bf(x0.y); v[2] = f2bf(x0.z); v[3] = f2bf(x0.w);
            v[4] = f2bf(x1.x); v[5] = f2bf(x1.y); v[6] = f2bf(x1.z); v[7] = f2bf(x1.w);
            af[m][kt] = v;
        }
    }

    // ---- q/k: 3 nt-pairs per wave, swapped operands, in-register normalize
#pragma unroll
    for (int jj = 0; jj < 3; jj++) {
        int j = w * 3 + jj;                 // pair 0..11: j<6 -> q head j, else k head j-6
        int nt0 = 2 * j, nt1 = 2 * j + 1;
        f32x4 bi0 = *(const f32x4*)(qkv_b + nt0 * 16 + q * 4);
        f32x4 bi1 = *(const f32x4*)(qkv_b + nt1 * 16 + q * 4);
        f32x4 a00 = bi0, a01 = bi0;
        f32x4 a10 = bi1, a11 = bi1;
#pragma unroll
        for (int kt = 0; kt < 6; kt++) {
            short8 b0 = ((const short8*)wqp)[(size_t)(nt0 * 6 + kt) * 64 + lane];
            short8 b1 = ((const short8*)wqp)[(size_t)(nt1 * 6 + kt) * 64 + lane];
            a00 = __builtin_amdgcn_mfma_f32_16x16x32_bf16(b0, af[0][kt], a00, 0, 0, 0);
            a01 = __builtin_amdgcn_mfma_f32_16x16x32_bf16(b0, af[1][kt], a01, 0, 0, 0);
            a10 = __builtin_amdgcn_mfma_f32_16x16x32_bf16(b1, af[0][kt], a10, 0, 0, 0);
            a11 = __builtin_amdgcn_mfma_f32_16x16x32_bf16(b1, af[1][kt], a11, 0, 0, 0);
        }
        float s0 = 0.f, s1 = 0.f;
#pragma unroll
        for (int reg = 0; reg < 4; reg++) {
            s0 += a00[reg] * a00[reg] + a10[reg] * a10[reg];
            s1 += a01[reg] * a01[reg] + a11[reg] * a11[reg];
        }
        s0 += __shfl_xor(s0, 16); s0 += __shfl_xor(s0, 32);
        s1 += __shfl_xor(s1, 16); s1 += __shfl_xor(s1, 32);
        float inv0 = 1.0f / fmaxf(sqrtf(s0), 1e-12f);
        float inv1 = 1.0f / fmaxf(sqrtf(s1), 1e-12f);
        int isq = j < 6;
        int h = isq ? j : j - 6;
        short* dst = (isq ? qbf : kbf) + (size_t)(b_ * 6 + h) * 8192;
        short4v v00, v10, v01, v11;
#pragma unroll
        for (int reg = 0; reg < 4; reg++) {
            v00[reg] = f2bf(a00[reg] * inv0);
            v10[reg] = f2bf(a10[reg] * inv0);
            v01[reg] = f2bf(a01[reg] * inv1);
            v11[reg] = f2bf(a11[reg] * inv1);
        }
        *(short4v*)(dst + (n0 + r) * 32 + q * 4) = v00;
        *(short4v*)(dst + (n0 + r) * 32 + 16 + q * 4) = v10;
        *(short4v*)(dst + (n0 + 16 + r) * 32 + q * 4) = v01;
        *(short4v*)(dst + (n0 + 16 + r) * 32 + 16 + q * 4) = v11;
    }

    // ---- v: 3 tiles per wave, unswapped, transposed bf16 out
#pragma unroll
    for (int jj = 0; jj < 3; jj++) {
        int nt = 24 + w * 3 + jj;
        float bias = qkv_b[nt * 16 + r];
        f32x4 a0 = {bias, bias, bias, bias};
        f32x4 a1 = {bias, bias, bias, bias};
#pragma unroll
        for (int kt = 0; kt < 6; kt++) {
            short8 bfr = ((const short8*)wqp)[(size_t)(nt * 6 + kt) * 64 + lane];
            a0 = __builtin_amdgcn_mfma_f32_16x16x32_bf16(af[0][kt], bfr, a0, 0, 0, 0);
            a1 = __builtin_amdgcn_mfma_f32_16x16x32_bf16(af[1][kt], bfr, a1, 0, 0, 0);
        }
        int ch = nt * 16 + r - 384;
        int hh = ch >> 5, dd = ch & 31;
        short* vb = vtb + ((size_t)(b_ * 6 + hh) * 32 + dd) * 256 + n0;
        short4v p0, p1;
#pragma unroll
        for (int reg = 0; reg < 4; reg++) { p0[reg] = f2bf(a0[reg]); p1[reg] = f2bf(a1[reg]); }
        *(short4v*)(vb + q * 4) = p0;
        *(short4v*)(vb + 16 + q * 4) = p1;
    }
}

// ---------------------------------------------------------------- K3: flash attention, SWAPPED-S, NO LDS STAGING
// R11: Ks/Vs were pure copies — every fragment read maps to a CONTIGUOUS 16B
// global load from kbf/vtb at the same index (K/V read by exactly one block,
// L2-resident). Dropping them removes the staging loop + barrier + 42.5KB LDS
// -> occupancy register-limited only. Same arithmetic, same output.
__global__ __launch_bounds__(256) void attn_mfma_k(const short* __restrict__ qbf,
                                                   const short* __restrict__ kbf,
                                                   const short* __restrict__ vtb,
                                                   const short* __restrict__ biasQK,
                                                   const float* __restrict__ logit_scale,
                                                   short* __restrict__ att) {
    int tid = threadIdx.x, lane = tid & 63, w = tid >> 6;
    int r = lane & 15, q = lane >> 4;
    int b_ = blockIdx.x / 6, h = blockIdx.x % 6;
    size_t base = (size_t)(b_ * 6 + h) * 8192;

    const short* kb = kbf + base;
    const short* vb = vtb + base;

    short8 qf[4];
#pragma unroll
    for (int mt = 0; mt < 4; mt++)
        qf[mt] = *(const short8*)(qbf + base + (size_t)(w * 64 + mt * 16 + r) * 32 + q * 8);

    float scale = __expf(fminf(logit_scale[h], 4.6051702f));
    float M = scale + 16.0f;
    int win = b_ & 127;
    int wt4 = (win >> 6) * 4, wh8 = ((win >> 3) & 7) * 8, ww8 = (win & 7) * 8;
    auto region = [&](int n) {
        int ts = wt4 + (n >> 6), hs = wh8 + ((n >> 3) & 7), wsv = ww8 + (n & 7);
        int rt = ts < 4 ? 0 : (ts < 6 ? 1 : 2);
        int rh = hs < 56 ? 0 : (hs < 60 ? 1 : 2);
        int rw = wsv < 56 ? 0 : (wsv < 60 ? 1 : 2);
        return rt * 9 + rh * 3 + rw;
    };
    int qreg[4];
#pragma unroll
    for (int mt = 0; mt < 4; mt++) qreg[mt] = region(w * 64 + mt * 16 + r);
    int rw4[4];
#pragma unroll
    for (int reg = 0; reg < 4; reg++) {
        int wsv = ww8 + (q & 1) * 4 + reg;
        rw4[reg] = wsv < 56 ? 0 : (wsv < 60 ? 1 : 2);
    }

    f32x4 O[4][2];
    float lpv[4];
#pragma unroll
    for (int mt = 0; mt < 4; mt++) {
        O[mt][0] = (f32x4){0.f, 0.f, 0.f, 0.f};
        O[mt][1] = (f32x4){0.f, 0.f, 0.f, 0.f};
        lpv[mt] = 0.f;
    }

    int qa = 2 * (q & 1);
    int srcA = (qa << 4) | r;
    int srcB = ((qa + 1) << 4) | r;
    bool loSel = q < 2;

    const short* bh = biasQK + ((size_t)h << 16);
    for (int s = 0; s < 8; s++) {
        short8 kf0 = *(const short8*)(kb + (size_t)(s * 32 + r) * 32 + q * 8);
        short8 kf1 = *(const short8*)(kb + (size_t)(s * 32 + 16 + r) * 32 + q * 8);
        short8 vf0 = *(const short8*)(vb + (size_t)r * 256 + s * 32 + q * 8);
        short8 vf1 = *(const short8*)(vb + (size_t)(16 + r) * 256 + s * 32 + q * 8);
        int ts = wt4 + (s >> 1);
        int rt_s = (ts < 4 ? 0 : (ts < 6 ? 1 : 2)) * 9;
        int hs0 = wh8 + (s & 1) * 4 + (q >> 1);
        int hs1 = hs0 + 2;
        int rh0 = (hs0 < 56 ? 0 : (hs0 < 60 ? 1 : 2)) * 3;
        int rh1 = (hs1 < 56 ? 0 : (hs1 < 60 ? 1 : 2)) * 3;
        int kreg0[4], kreg1[4];
#pragma unroll
        for (int reg = 0; reg < 4; reg++) {
            kreg0[reg] = rt_s + rh0 + rw4[reg];
            kreg1[reg] = rt_s + rh1 + rw4[reg];
        }
#pragma unroll
        for (int mt = 0; mt < 4; mt++) {
            f32x4 s0 = {0.f, 0.f, 0.f, 0.f};
            f32x4 s1 = {0.f, 0.f, 0.f, 0.f};
            s0 = __builtin_amdgcn_mfma_f32_16x16x32_bf16(kf0, qf[mt], s0, 0, 0, 0);
            s1 = __builtin_amdgcn_mfma_f32_16x16x32_bf16(kf1, qf[mt], s1, 0, 0, 0);
            int query = w * 64 + mt * 16 + r;
            short8 bv = *(const short8*)(bh + (size_t)query * 256 + s * 32 + q * 8);
            float p0[4], p1[4];
            float lsum = 0.f;
#pragma unroll
            for (int reg = 0; reg < 4; reg++) {
                float bb0 = h2f(bv[2 * reg]);
                float bb1 = h2f(bv[2 * reg + 1]);
                float v0 = s0[reg] * scale + bb0 + (kreg0[reg] == qreg[mt] ? 0.f : -100.f) - M;
                float v1 = s1[reg] * scale + bb1 + (kreg1[reg] == qreg[mt] ? 0.f : -100.f) - M;
                p0[reg] = __expf(v0);
                p1[reg] = __expf(v1);
                lsum += p0[reg] + p1[reg];
            }
            lpv[mt] += lsum;
            unsigned lo0 = pk2bf(p0[0], p0[1]);
            unsigned lo1 = pk2bf(p0[2], p0[3]);
            unsigned hi0 = pk2bf(p1[0], p1[1]);
            unsigned hi1 = pk2bf(p1[2], p1[3]);
            unsigned a0 = __shfl((int)lo0, srcA);
            unsigned a1 = __shfl((int)lo1, srcA);
            unsigned a2 = __shfl((int)lo0, srcB);
            unsigned a3 = __shfl((int)lo1, srcB);
            unsigned b0 = __shfl((int)hi0, srcA);
            unsigned b1 = __shfl((int)hi1, srcA);
            unsigned b2 = __shfl((int)hi0, srcB);
            unsigned b3 = __shfl((int)hi1, srcB);
            union { unsigned u[4]; short8 s8; } pu;
            pu.u[0] = loSel ? a0 : b0;
            pu.u[1] = loSel ? a1 : b1;
            pu.u[2] = loSel ? a2 : b2;
            pu.u[3] = loSel ? a3 : b3;
            short8 pb = pu.s8;
            O[mt][0] = __builtin_amdgcn_mfma_f32_16x16x32_bf16(vf0, pb, O[mt][0], 0, 0, 0);
            O[mt][1] = __builtin_amdgcn_mfma_f32_16x16x32_bf16(vf1, pb, O[mt][1], 0, 0, 0);
        }
    }

#pragma unroll
    for (int mt = 0; mt < 4; mt++) {
        float v = lpv[mt];
        v += __shfl_xor(v, 16);
        v += __shfl_xor(v, 32);
        lpv[mt] = 1.0f / v;
    }
#pragma unroll
    for (int mt = 0; mt < 4; mt++) {
        float linv = lpv[mt];
        int query = w * 64 + mt * 16 + r;
        short* dst = att + ((size_t)b_ * 256 + query) * 192 + h * 32 + q * 4;
#pragma unroll
        for (int nt = 0; nt < 2; nt++) {
            short4v pv;
#pragma unroll
            for (int reg = 0; reg < 4; reg++) pv[reg] = f2bf(O[mt][nt][reg] * linv);
            *(short4v*)(dst + nt * 16) = pv;
        }
    }
}

// ---------------------------------------------------------------- K4: out-proj via bf16 MFMA (swapped operands) + LN + roll-scatter + residual
__global__ __launch_bounds__(256) void proj_mfma_k(const short* __restrict__ att,
                                                   const short* __restrict__ wpp,
                                                   const float* __restrict__ proj_b,
                                                   const float* __restrict__ x,
                                                   const float* __restrict__ g1,
                                                   const float* __restrict__ b1n,
                                                   float* __restrict__ out,
                                                   short* __restrict__ xmb) {
    __shared__ float ps[32][4], pss[32][4];
    __shared__ float mean_s[32], inv_s[32];
    int tid = threadIdx.x, lane = tid & 63, w = tid >> 6;
    int r = lane & 15, q = lane >> 4;
    int b_ = blockIdx.x >> 3, n0 = (blockIdx.x & 7) << 5;

    short8 af[2][6];
#pragma unroll
    for (int m = 0; m < 2; m++) {
        const short* src = att + ((size_t)b_ * 256 + n0 + m * 16 + r) * 192 + q * 8;
#pragma unroll
        for (int kt = 0; kt < 6; kt++)
            af[m][kt] = *(const short8*)(src + kt * 32);
    }
    f32x4 acc[3][2];
#pragma unroll
    for (int ntl = 0; ntl < 3; ntl++) {
        int nt = w * 3 + ntl;
        f32x4 binit = *(const f32x4*)(proj_b + nt * 16 + q * 4);
        short8 bfr[6];
#pragma unroll
        for (int kt = 0; kt < 6; kt++)
            bfr[kt] = ((const short8*)wpp)[(size_t)(nt * 6 + kt) * 64 + lane];
        f32x4 a0 = binit, a1 = binit;
#pragma unroll
        for (int kt = 0; kt < 6; kt++) {
            a0 = __builtin_amdgcn_mfma_f32_16x16x32_bf16(bfr[kt], af[0][kt], a0, 0, 0, 0);
            a1 = __builtin_amdgcn_mfma_f32_16x16x32_bf16(bfr[kt], af[1][kt], a1, 0, 0, 0);
        }
        acc[ntl][0] = a0;
        acc[ntl][1] = a1;
    }
    float s0 = 0.f, ss0 = 0.f, s1 = 0.f, ss1 = 0.f;
#pragma unroll
    for (int ntl = 0; ntl < 3; ntl++)
#pragma unroll
        for (int reg = 0; reg < 4; reg++) {
            float z0 = acc[ntl][0][reg], z1 = acc[ntl][1][reg];
            s0 += z0; ss0 += z0 * z0;
            s1 += z1; ss1 += z1 * z1;
        }
    s0 += __shfl_xor(s0, 16); ss0 += __shfl_xor(ss0, 16);
    s0 += __shfl_xor(s0, 32); ss0 += __shfl_xor(ss0, 32);
    s1 += __shfl_xor(s1, 16); ss1 += __shfl_xor(ss1, 16);
    s1 += __shfl_xor(s1, 32); ss1 += __shfl_xor(ss1, 32);
    if (q == 0) {
        ps[r][w] = s0;  pss[r][w] = ss0;
        ps[16 + r][w] = s1;  pss[16 + r][w] = ss1;
    }
    __syncthreads();
    if (tid < 32) {
        float sm = ps[tid][0] + ps[tid][1] + ps[tid][2] + ps[tid][3];
        float sq = pss[tid][0] + pss[tid][1] + pss[tid][2] + pss[tid][3];
        float mean = sm * (1.0f / 192.0f);
        float var = sq * (1.0f / 192.0f) - mean * mean;
        mean_s[tid] = mean;
        inv_s[tid] = 1.0f / sqrtf(var + 1e-5f);
    }
    __syncthreads();
    int b = b_ >> 7, win = b_ & 127;
    int wt = win >> 6, wh = (win >> 3) & 7, ww = win & 7;
#pragma unroll
    for (int mh = 0; mh < 2; mh++) {
        int token = mh * 16 + r;
        int n = n0 + token;
        int t0 = ((wt * 4 + (n >> 6)) + 2) & 7;
        int h0 = ((wh * 8 + ((n >> 3) & 7)) + 4) & 63;
        int w0 = ((ww * 8 + (n & 7)) + 4) & 63;
        size_t gb = ((size_t)((b * 8 + t0) * 64 + h0) * 64 + w0) * 192;
        float mean = mean_s[token], inv = inv_s[token];
#pragma unroll
        for (int ntl = 0; ntl < 3; ntl++) {
            int ch = (w * 3 + ntl) * 16 + q * 4;
            f32x4 zv = acc[ntl][mh];
            f32x4 gv = *(const f32x4*)(g1 + ch);
            f32x4 bv = *(const f32x4*)(b1n + ch);
            f32x4 xv = *(const f32x4*)(x + gb + ch);
            f32x4 o;
            short4v xm;
#pragma unroll
            for (int j = 0; j < 4; j++) {
                o[j] = xv[j] + (zv[j] - mean) * inv * gv[j] + bv[j];
                xm[j] = f2bf(o[j]);
            }
            *(f32x4*)(out + gb + ch) = o;
            *(short4v*)(xmb + gb + ch) = xm;
        }
    }
}

// ---------------------------------------------------------------- K5: MLP — R9 form (Xs staging), PERMANENT
// R3+R10 both proved: mlp's live state (~90 regs) needs the 65-128 VGPR band ->
// 4 waves/SIMD is its hard ceiling; any attempt at 8 waves/SIMD (VGPR<=64)
// spills to scratch (+400MB HBM, 2x slower). The Xs staging loop anchors the
// allocator at 56 VGPR / no spill. Do not drop Xs again.
#define XSTR 200
#define H2STR 264
__global__ __launch_bounds__(512, 4) void mlp_mfma_k(const short* __restrict__ xmb,
                                                     const short* __restrict__ w1p,
                                                     const short* __restrict__ w2p,
                                                     const float* __restrict__ fc1_b,
                                                     const float* __restrict__ fc2_b,
                                                     const float* __restrict__ g2,
                                                     const float* __restrict__ b2,
                                                     float* __restrict__ out) {
    __shared__ short Xs[64 * XSTR];   // 25600 B
    __shared__ short Hs[64 * H2STR];  // 33792 B
    __shared__ float ps[64][4], pss[64][4];
    __shared__ float mean_s[64], inv_s[64];
    int tid = threadIdx.x;
    int lane = tid & 63, w = tid >> 6;
    int r = lane & 15, q = lane >> 4;
    size_t tok0 = (size_t)blockIdx.x * 64;

    for (int i = tid; i < 1536; i += 512) {
        int token = i / 24, ch8 = (i - token * 24) * 8;
        short8 v = *(const short8*)(xmb + (tok0 + token) * 192 + ch8);
        *(short8*)&Xs[token * XSTR + ch8] = v;
    }
    __syncthreads();

    int mg = w >> 2;
    int ng = w & 3;
    f32x4 acc2[6];
#pragma unroll
    for (int i = 0; i < 6; i++) acc2[i] = (f32x4){0.f, 0.f, 0.f, 0.f};

    for (int c = 0; c < 3; c++) {
        {
            int ntg0 = c * 16 + 2 * w;
            f32x4 a[2][4];
#pragma unroll
            for (int ntl = 0; ntl < 2; ntl++) {
                f32x4 binit = *(const f32x4*)(fc1_b + (ntg0 + ntl) * 16 + q * 4);
#pragma unroll
                for (int m = 0; m < 4; m++) a[ntl][m] = binit;
            }
#pragma unroll
            for (int kt = 0; kt < 6; kt++) {
                short8 w0 = ((const short8*)w1p)[(size_t)((ntg0) * 6 + kt) * 64 + lane];
                short8 w1f = ((const short8*)w1p)[(size_t)((ntg0 + 1) * 6 + kt) * 64 + lane];
                short8 xb[4];
#pragma unroll
                for (int m = 0; m < 4; m++)
                    xb[m] = *(const short8*)&Xs[(m * 16 + r) * XSTR + kt * 32 + q * 8];
#pragma unroll
                for (int m = 0; m < 4; m++) {
                    a[0][m] = __builtin_amdgcn_mfma_f32_16x16x32_bf16(w0, xb[m], a[0][m], 0, 0, 0);
                    a[1][m] = __builtin_amdgcn_mfma_f32_16x16x32_bf16(w1f, xb[m], a[1][m], 0, 0, 0);
                }
            }
#pragma unroll
            for (int ntl = 0; ntl < 2; ntl++) {
                int hcol = (2 * w + ntl) * 16 + q * 4;
#pragma unroll
                for (int m = 0; m < 4; m++) {
                    short4v p;
#pragma unroll
                    for (int reg = 0; reg < 4; reg++) p[reg] = f2bf(gelu_fast(a[ntl][m][reg]));
                    *(short4v*)&Hs[(m * 16 + r) * H2STR + hcol] = p;
                }
            }
        }
        __syncthreads();

#pragma unroll
        for (int kk = 0; kk < 8; kk++) {
            short8 hb0 = *(const short8*)&Hs[((mg * 2) * 16 + r) * H2STR + kk * 32 + q * 8];
            short8 hb1 = *(const short8*)&Hs[((mg * 2 + 1) * 16 + r) * H2STR + kk * 32 + q * 8];
            int kkg = c * 8 + kk;
#pragma unroll
            for (int n = 0; n < 3; n++) {
                int ntz = ng * 3 + n;
                short8 wf = ((const short8*)w2p)[(size_t)(ntz * 24 + kkg) * 64 + lane];
                acc2[n * 2 + 0] = __builtin_amdgcn_mfma_f32_16x16x32_bf16(wf, hb0, acc2[n * 2 + 0], 0, 0, 0);
                acc2[n * 2 + 1] = __builtin_amdgcn_mfma_f32_16x16x32_bf16(wf, hb1, acc2[n * 2 + 1], 0, 0, 0);
            }
        }
        __syncthreads();
    }

    float s0 = 0.f, ss0 = 0.f, s1 = 0.f, ss1 = 0.f;
#pragma unroll
    for (int n = 0; n < 3; n++) {
        f32x4 b4 = *(const f32x4*)(fc2_b + (ng * 3 + n) * 16 + q * 4);
        f32x4 z0 = acc2[n * 2 + 0] + b4;
        f32x4 z1 = acc2[n * 2 + 1] + b4;
        acc2[n * 2 + 0] = z0;
        acc2[n * 2 + 1] = z1;
#pragma unroll
        for (int reg = 0; reg < 4; reg++) {
            s0 += z0[reg]; ss0 += z0[reg] * z0[reg];
            s1 += z1[reg]; ss1 += z1[reg] * z1[reg];
        }
    }
    s0 += __shfl_xor(s0, 16); ss0 += __shfl_xor(ss0, 16);
    s0 += __shfl_xor(s0, 32); ss0 += __shfl_xor(ss0, 32);
    s1 += __shfl_xor(s1, 16); ss1 += __shfl_xor(ss1, 16);
    s1 += __shfl_xor(s1, 32); ss1 += __shfl_xor(ss1, 32);
    if (q == 0) {
        int t0 = mg * 32 + r;
        ps[t0][ng] = s0;  pss[t0][ng] = ss0;
        ps[t0 + 16][ng] = s1;  pss[t0 + 16][ng] = ss1;
    }
    __syncthreads();
    if (tid < 64) {
        float sm = ps[tid][0] + ps[tid][1] + ps[tid][2] + ps[tid][3];
        float sq = pss[tid][0] + pss[tid][1] + pss[tid][2] + pss[tid][3];
        float mean = sm * (1.0f / 192.0f);
        float var = sq * (1.0f / 192.0f) - mean * mean;
        mean_s[tid] = mean;
        inv_s[tid] = 1.0f / sqrtf(var + 1e-5f);
    }
    __syncthreads();
#pragma unroll
    for (int n = 0; n < 3; n++) {
        int ntz = ng * 3 + n;
        f32x4 g4 = *(const f32x4*)(g2 + ntz * 16 + q * 4);
        f32x4 bb4 = *(const f32x4*)(b2 + ntz * 16 + q * 4);
#pragma unroll
        for (int mh = 0; mh < 2; mh++) {
            int token = mg * 32 + mh * 16 + r;
            float mean = mean_s[token], inv = inv_s[token];
            size_t gi = (tok0 + token) * 192 + ntz * 16 + q * 4;
            f32x4 o = *(const f32x4*)(out + gi);
            f32x4 z = acc2[n * 2 + mh];
            f32x4 res;
#pragma unroll
            for (int reg = 0; reg < 4; reg++)
                res[reg] = o[reg] + (z[reg] - mean) * inv * g4[reg] + bb4[reg];
            *(f32x4*)(out + gi) = res;
        }
    }
}

// ---------------------------------------------------------------- launch
extern "C" void kernel_launch(void* const* d_in, const int* in_sizes, int n_in,
                              void* d_out, int out_size, void* d_ws, size_t ws_size,
                              hipStream_t stream) {
    const float* x           = (const float*)d_in[0];
    const float* qkv_w       = (const float*)d_in[1];
    const float* qkv_b       = (const float*)d_in[2];
    const float* proj_w      = (const float*)d_in[3];
    const float* proj_b      = (const float*)d_in[4];
    const float* cpb_w1      = (const float*)d_in[5];
    const float* cpb_b1      = (const float*)d_in[6];
    const float* cpb_w2      = (const float*)d_in[7];
    const float* logit_scale = (const float*)d_in[8];
    const float* norm1_g     = (const float*)d_in[9];
    const float* norm1_b     = (const float*)d_in[10];
    const float* norm2_g     = (const float*)d_in[11];
    const float* norm2_b     = (const float*)d_in[12];
    const float* fc1_w       = (const float*)d_in[13];
    const float* fc1_b       = (const float*)d_in[14];
    const float* fc2_w       = (const float*)d_in[15];
    const float* fc2_b       = (const float*)d_in[16];
    float* out = (float*)d_out;

    float* ws = (float*)d_ws;
    const size_t QKVE = (size_t)256 * 6 * 256 * 32;   // 12,582,912 elems
    short* att    = (short*)ws;                       // bf16, region kept fp32-sized
    short* biasQK = (short*)(ws + QKVE);              // fp16 packed, 393,216 shorts
    float* tbl6   = ws + QKVE + (size_t)6 * 256 * 256;  // 9,450 fp32
    short* w1pack = (short*)(tbl6 + 9472);
    short* w2pack = w1pack + (size_t)768 * 192;
    short* wqpack = w2pack + (size_t)192 * 768;
    short* wppack = wqpack + (size_t)576 * 192;
    short* qbf    = wppack + (size_t)192 * 192;       // bf16, 12,582,912 each
    short* kbf    = qbf + QKVE;
    short* vtb    = kbf + QKVE;
    short* xmb    = vtb + QKVE;                       // bf16 x_mid, raster order

    hipLaunchKernelGGL(setup_k, dim3(2439), dim3(64), 0, stream,
                       fc1_w, w1pack, fc2_w, w2pack, qkv_w, wqpack, proj_w, wppack,
                       cpb_w1, cpb_b1, cpb_w2, tbl6);
    hipLaunchKernelGGL(bias_k, dim3(1536), dim3(256), 0, stream, tbl6, biasQK);
    hipLaunchKernelGGL(qkv_mfma_k, dim3(2048), dim3(256), 0, stream, x, wqpack, qkv_b, qbf, kbf, vtb);
    hipLaunchKernelGGL(attn_mfma_k, dim3(1536), dim3(256), 0, stream, qbf, kbf, vtb, biasQK, logit_scale, att);
    hipLaunchKernelGGL(proj_mfma_k, dim3(2048), dim3(256), 0, stream, att, wppack, proj_b, x, norm1_g, norm1_b, out, xmb);
    hipLaunchKernelGGL(mlp_mfma_k, dim3(1024), dim3(512), 0, stream, xmb, w1pack, w2pack,
                       fc1_b, fc2_b, norm2_g, norm2_b, out);
}

// Round 12
// 345.643 us; speedup vs baseline: 1.2919x; 1.0177x over previous
//
#include <hip/hip_runtime.h>
#include <math.h>

// Problem constants
// B=2, T=8, H=64, W=64, C=192, WIN=(4,8,8), SHIFT=(2,4,4), HEADS=6, d=32
// N=256 tokens/window, nW=128 windows/batch, B_=256 windows total, HID=768

typedef short short8 __attribute__((ext_vector_type(8)));
typedef short short4v __attribute__((ext_vector_type(4)));
typedef float f32x4 __attribute__((ext_vector_type(4)));

__device__ __forceinline__ short f2bf(float f) {
    union { float f; unsigned u; } v; v.f = f;
    unsigned r = v.u + 0x7FFF + ((v.u >> 16) & 1);  // RNE
    return (short)(r >> 16);
}
__device__ __forceinline__ unsigned pk2bf(float lo, float hi) {
    return ((unsigned)(unsigned short)f2bf(lo)) | (((unsigned)(unsigned short)f2bf(hi)) << 16);
}
__device__ __forceinline__ short f2h(float f) {
    _Float16 h = (_Float16)f;
    union { _Float16 h; short s; } u; u.h = h; return u.s;
}
__device__ __forceinline__ float h2f(short s) {
    union { _Float16 h; short s; } u; u.s = s; return (float)u.h;
}

// tanh-form GELU reduced to sigmoid: x * sigmoid(1.5957691*x*(1+0.044715*x^2))
__device__ __forceinline__ float gelu_fast(float x) {
    float s = x * x;
    float t = fmaf(0.044715f, s, 1.0f);
    float y = -1.5957691216057308f * x * t;
    return x * __builtin_amdgcn_rcpf(1.0f + __expf(y));
}

// ---------------------------------------------------------------- K0: fused setup — 4 weight packs + CPB table in ONE launch
__device__ __forceinline__ void pack_w_dev(const float* __restrict__ w,
                                           short* __restrict__ dst, int K, int bid,
                                           int lane) {
    int ktn = K >> 5;
    int nt = bid / ktn, kt = bid % ktn;
    int r = lane & 15, q = lane >> 4;
    const float* src = w + (size_t)(nt * 16 + r) * K + kt * 32 + q * 8;
    short8 v;
#pragma unroll
    for (int j = 0; j < 8; j++) v[j] = f2bf(src[j]);
    ((short8*)dst)[(size_t)bid * 64 + lane] = v;
}

__global__ __launch_bounds__(64) void setup_k(const float* __restrict__ fc1_w, short* __restrict__ w1p,
                                              const float* __restrict__ fc2_w, short* __restrict__ w2p,
                                              const float* __restrict__ qkv_w, short* __restrict__ wqp,
                                              const float* __restrict__ proj_w, short* __restrict__ wpp,
                                              const float* __restrict__ cw1, const float* __restrict__ cb1,
                                              const float* __restrict__ cw2, float* __restrict__ tbl6) {
    int bid = blockIdx.x;
    int lane = threadIdx.x;
    if (bid < 288) { pack_w_dev(fc1_w, w1p, 192, bid, lane); return; }
    if (bid < 576) { pack_w_dev(fc2_w, w2p, 768, bid - 288, lane); return; }
    if (bid < 792) { pack_w_dev(qkv_w, wqp, 192, bid - 576, lane); return; }
    if (bid < 864) { pack_w_dev(proj_w, wpp, 192, bid - 792, lane); return; }
    int m = bid - 864;
    int it = m / 225;
    int ih = (m / 15) % 15;
    int iw = m % 15;
    float r0 = (float)(it - 3) * (8.0f / 3.0f);
    float r1 = (float)(ih - 7) * (8.0f / 7.0f);
    float r2 = (float)(iw - 7) * (8.0f / 7.0f);
    float c0 = (r0 < 0.f ? -1.f : 1.f) * log2f(fabsf(r0) + 1.0f) * (1.0f / 3.0f);
    float c1 = (r1 < 0.f ? -1.f : 1.f) * log2f(fabsf(r1) + 1.0f) * (1.0f / 3.0f);
    float c2 = (r2 < 0.f ? -1.f : 1.f) * log2f(fabsf(r2) + 1.0f) * (1.0f / 3.0f);
    float hv[8];
#pragma unroll
    for (int j = 0; j < 8; j++) {
        int t = lane * 8 + j;
        hv[j] = fmaxf(0.0f, c0 * cw1[3 * t] + c1 * cw1[3 * t + 1] + c2 * cw1[3 * t + 2] + cb1[t]);
    }
#pragma unroll
    for (int head = 0; head < 6; head++) {
        float s = 0.f;
#pragma unroll
        for (int j = 0; j < 8; j++) s += hv[j] * cw2[head * 512 + lane * 8 + j];
        s += __shfl_xor(s, 1);
        s += __shfl_xor(s, 2);
        s += __shfl_xor(s, 4);
        s += __shfl_xor(s, 8);
        s += __shfl_xor(s, 16);
        s += __shfl_xor(s, 32);
        if (lane == 0) tbl6[m * 6 + head] = s;
    }
}

// ---------------------------------------------------------------- K1b: fp16 bias, PLAIN layout [h][query(256)][key(256)]
// R12: attn's key permutation makes the lane's 8 needed biases CONTIGUOUS
// (keys s*32+q*8..+7) -> one 16B load, no interleave needed.
__global__ __launch_bounds__(256) void bias_k(const float* __restrict__ tbl6,
                                              short* __restrict__ biasQK) {
    int idx = blockIdx.x * 256 + threadIdx.x;
    int key = idx & 255;
    int query = (idx >> 8) & 255;
    int h = idx >> 16;
    int dt = (query >> 6) - (key >> 6) + 3;
    int dh = ((query >> 3) & 7) - ((key >> 3) & 7) + 7;
    int dw = (query & 7) - (key & 7) + 7;
    int rel = dt * 225 + dh * 15 + dw;
    float v = tbl6[rel * 6 + h];
    biasQK[idx] = f2h(16.0f / (1.0f + expf(-v)));
}

// ---------------------------------------------------------------- K2: QKV — registers-only normalize, NO LDS (R9, verified)
__global__ __launch_bounds__(256) void qkv_mfma_k(const float* __restrict__ x,
                                                  const short* __restrict__ wqp,
                                                  const float* __restrict__ qkv_b,
                                                  short* __restrict__ qbf,
                                                  short* __restrict__ kbf,
                                                  short* __restrict__ vtb) {
    int tid = threadIdx.x, lane = tid & 63, w = tid >> 6;
    int r = lane & 15, q = lane >> 4;
    int b_ = blockIdx.x >> 3, n0 = (blockIdx.x & 7) << 5;
    int b = b_ >> 7, win = b_ & 127;
    int wt = win >> 6, wh = (win >> 3) & 7, ww = win & 7;

    short8 af[2][6];
#pragma unroll
    for (int m = 0; m < 2; m++) {
        int n = n0 + m * 16 + r;
        int t0 = ((wt * 4 + (n >> 6)) + 2) & 7;
        int h0 = ((wh * 8 + ((n >> 3) & 7)) + 4) & 63;
        int w0 = ((ww * 8 + (n & 7)) + 4) & 63;
        const float* src = x + ((size_t)((b * 8 + t0) * 64 + h0) * 64 + w0) * 192 + q * 8;
#pragma unroll
        for (int kt = 0; kt < 6; kt++) {
            float4 x0 = *(const float4*)(src + kt * 32);
            float4 x1 = *(const float4*)(src + kt * 32 + 4);
            short8 v;
            v[0] = f2bf(x0.x); v[1] = f2bf(x0.y); v[2] = f2bf(x0.z); v[3] = f2bf(x0.w);
            v[4] = f2bf(x1.x); v[5] = f2bf(x1.y); v[6] = f2bf(x1.z); v[7] = f2bf(x1.w);
            af[m][kt] = v;
        }
    }

    // ---- q/k: 3 nt-pairs per wave, swapped operands, in-register normalize
#pragma unroll
    for (int jj = 0; jj < 3; jj++) {
        int j = w * 3 + jj;                 // pair 0..11: j<6 -> q head j, else k head j-6
        int nt0 = 2 * j, nt1 = 2 * j + 1;
        f32x4 bi0 = *(const f32x4*)(qkv_b + nt0 * 16 + q * 4);
        f32x4 bi1 = *(const f32x4*)(qkv_b + nt1 * 16 + q * 4);
        f32x4 a00 = bi0, a01 = bi0;
        f32x4 a10 = bi1, a11 = bi1;
#pragma unroll
        for (int kt = 0; kt < 6; kt++) {
            short8 b0 = ((const short8*)wqp)[(size_t)(nt0 * 6 + kt) * 64 + lane];
            short8 b1 = ((const short8*)wqp)[(size_t)(nt1 * 6 + kt) * 64 + lane];
            a00 = __builtin_amdgcn_mfma_f32_16x16x32_bf16(b0, af[0][kt], a00, 0, 0, 0);
            a01 = __builtin_amdgcn_mfma_f32_16x16x32_bf16(b0, af[1][kt], a01, 0, 0, 0);
            a10 = __builtin_amdgcn_mfma_f32_16x16x32_bf16(b1, af[0][kt], a10, 0, 0, 0);
            a11 = __builtin_amdgcn_mfma_f32_16x16x32_bf16(b1, af[1][kt], a11, 0, 0, 0);
        }
        float s0 = 0.f, s1 = 0.f;
#pragma unroll
        for (int reg = 0; reg < 4; reg++) {
            s0 += a00[reg] * a00[reg] + a10[reg] * a10[reg];
            s1 += a01[reg] * a01[reg] + a11[reg] * a11[reg];
        }
        s0 += __shfl_xor(s0, 16); s0 += __shfl_xor(s0, 32);
        s1 += __shfl_xor(s1, 16); s1 += __shfl_xor(s1, 32);
        float inv0 = 1.0f / fmaxf(sqrtf(s0), 1e-12f);
        float inv1 = 1.0f / fmaxf(sqrtf(s1), 1e-12f);
        int isq = j < 6;
        int h = isq ? j : j - 6;
        short* dst = (isq ? qbf : kbf) + (size_t)(b_ * 6 + h) * 8192;
        short4v v00, v10, v01, v11;
#pragma unroll
        for (int reg = 0; reg < 4; reg++) {
            v00[reg] = f2bf(a00[reg] * inv0);
            v10[reg] = f2bf(a10[reg] * inv0);
            v01[reg] = f2bf(a01[reg] * inv1);
            v11[reg] = f2bf(a11[reg] * inv1);
        }
        *(short4v*)(dst + (n0 + r) * 32 + q * 4) = v00;
        *(short4v*)(dst + (n0 + r) * 32 + 16 + q * 4) = v10;
        *(short4v*)(dst + (n0 + 16 + r) * 32 + q * 4) = v01;
        *(short4v*)(dst + (n0 + 16 + r) * 32 + 16 + q * 4) = v11;
    }

    // ---- v: 3 tiles per wave, unswapped, transposed bf16 out
#pragma unroll
    for (int jj = 0; jj < 3; jj++) {
        int nt = 24 + w * 3 + jj;
        float bias = qkv_b[nt * 16 + r];
        f32x4 a0 = {bias, bias, bias, bias};
        f32x4 a1 = {bias, bias, bias, bias};
#pragma unroll
        for (int kt = 0; kt < 6; kt++) {
            short8 bfr = ((const short8*)wqp)[(size_t)(nt * 6 + kt) * 64 + lane];
            a0 = __builtin_amdgcn_mfma_f32_16x16x32_bf16(af[0][kt], bfr, a0, 0, 0, 0);
            a1 = __builtin_amdgcn_mfma_f32_16x16x32_bf16(af[1][kt], bfr, a1, 0, 0, 0);
        }
        int ch = nt * 16 + r - 384;
        int hh = ch >> 5, dd = ch & 31;
        short* vb = vtb + ((size_t)(b_ * 6 + hh) * 32 + dd) * 256 + n0;
        short4v p0, p1;
#pragma unroll
        for (int reg = 0; reg < 4; reg++) { p0[reg] = f2bf(a0[reg]); p1[reg] = f2bf(a1[reg]); }
        *(short4v*)(vb + q * 4) = p0;
        *(short4v*)(vb + 16 + q * 4) = p1;
    }
}

// ---------------------------------------------------------------- K3: flash attention, SWAPPED-S + KEY-PERMUTED (zero-shuffle P)
// R12: key order inside each 32-key s-block is arbitrary. Stage QK A-rows so
// kf0 rows = keys {8q+i} (row 4q+i <-> key 8q+i), kf1 rows = keys {8q+4+i}.
// Then lane (q,r) holds P for keys 8q..8q+7 == the PV B-frag slot set:
// B-frag = 4 pk2bf packs. ZERO shuffles/selects (was 256 ds_bpermute +
// 128 cndmask per wave — same LDS-pipe traffic as the pre-R8 Ps roundtrip,
// which is why R8/R11 were flat). Bias is 8 contiguous fp16 per lane.
__global__ __launch_bounds__(256) void attn_mfma_k(const short* __restrict__ qbf,
                                                   const short* __restrict__ kbf,
                                                   const short* __restrict__ vtb,
                                                   const short* __restrict__ biasQK,
                                                   const float* __restrict__ logit_scale,
                                                   short* __restrict__ att) {
    int tid = threadIdx.x, lane = tid & 63, w = tid >> 6;
    int r = lane & 15, q = lane >> 4;
    int b_ = blockIdx.x / 6, h = blockIdx.x % 6;
    size_t base = (size_t)(b_ * 6 + h) * 8192;

    const short* kb = kbf + base;
    const short* vb = vtb + base;

    short8 qf[4];
#pragma unroll
    for (int mt = 0; mt < 4; mt++)
        qf[mt] = *(const short8*)(qbf + base + (size_t)(w * 64 + mt * 16 + r) * 32 + q * 8);

    float scale = __expf(fminf(logit_scale[h], 4.6051702f));
    float M = scale + 16.0f;
    int win = b_ & 127;
    int wt4 = (win >> 6) * 4, wh8 = ((win >> 3) & 7) * 8, ww8 = (win & 7) * 8;
    auto region = [&](int n) {
        int ts = wt4 + (n >> 6), hs = wh8 + ((n >> 3) & 7), wsv = ww8 + (n & 7);
        int rt = ts < 4 ? 0 : (ts < 6 ? 1 : 2);
        int rh = hs < 56 ? 0 : (hs < 60 ? 1 : 2);
        int rw = wsv < 56 ? 0 : (wsv < 60 ? 1 : 2);
        return rt * 9 + rh * 3 + rw;
    };
    int qreg[4];
#pragma unroll
    for (int mt = 0; mt < 4; mt++) qreg[mt] = region(w * 64 + mt * 16 + r);
    // key = s*32 + q*8 + c (c=0..7): w-component region depends only on c
    int rwc[8];
#pragma unroll
    for (int c = 0; c < 8; c++) {
        int wsv = ww8 + c;
        rwc[c] = wsv < 56 ? 0 : (wsv < 60 ? 1 : 2);
    }

    f32x4 O[4][2];
    float lpv[4];
#pragma unroll
    for (int mt = 0; mt < 4; mt++) {
        O[mt][0] = (f32x4){0.f, 0.f, 0.f, 0.f};
        O[mt][1] = (f32x4){0.f, 0.f, 0.f, 0.f};
        lpv[mt] = 0.f;
    }

    // permuted K row base: row r of kf0 -> key (r>>2)*8 + (r&3); kf1 -> +4
    int krow = ((r >> 2) << 3) + (r & 3);

    const short* bh = biasQK + ((size_t)h << 16);
    for (int s = 0; s < 8; s++) {
        short8 kf0 = *(const short8*)(kb + (size_t)(s * 32 + krow) * 32 + q * 8);
        short8 kf1 = *(const short8*)(kb + (size_t)(s * 32 + krow + 4) * 32 + q * 8);
        short8 vf0 = *(const short8*)(vb + (size_t)r * 256 + s * 32 + q * 8);
        short8 vf1 = *(const short8*)(vb + (size_t)(16 + r) * 256 + s * 32 + q * 8);
        // key region: rt from s, rh from (s&1, q) — same for both halves; rw = rwc[c]
        int ts = wt4 + (s >> 1);
        int rt_s = (ts < 4 ? 0 : (ts < 6 ? 1 : 2)) * 9;
        int hsq = wh8 + (s & 1) * 4 + q;
        int rhq = (hsq < 56 ? 0 : (hsq < 60 ? 1 : 2)) * 3;
        int kregc[8];
#pragma unroll
        for (int c = 0; c < 8; c++) kregc[c] = rt_s + rhq + rwc[c];
#pragma unroll
        for (int mt = 0; mt < 4; mt++) {
            f32x4 s0 = {0.f, 0.f, 0.f, 0.f};
            f32x4 s1 = {0.f, 0.f, 0.f, 0.f};
            // swapped: A=K frag (rows=permuted keys), B=Q frag (cols=queries)
            s0 = __builtin_amdgcn_mfma_f32_16x16x32_bf16(kf0, qf[mt], s0, 0, 0, 0);
            s1 = __builtin_amdgcn_mfma_f32_16x16x32_bf16(kf1, qf[mt], s1, 0, 0, 0);
            int query = w * 64 + mt * 16 + r;
            // 8 contiguous fp16: keys s*32 + q*8 .. +7
            short8 bv = *(const short8*)(bh + (size_t)query * 256 + s * 32 + q * 8);
            float p0[4], p1[4];
            float lsum = 0.f;
#pragma unroll
            for (int reg = 0; reg < 4; reg++) {
                float bb0 = h2f(bv[reg]);          // key q*8+reg
                float bb1 = h2f(bv[4 + reg]);      // key q*8+4+reg
                float v0 = s0[reg] * scale + bb0 + (kregc[reg] == qreg[mt] ? 0.f : -100.f) - M;
                float v1 = s1[reg] * scale + bb1 + (kregc[4 + reg] == qreg[mt] ? 0.f : -100.f) - M;
                p0[reg] = __expf(v0);
                p1[reg] = __expf(v1);
                lsum += p0[reg] + p1[reg];
            }
            lpv[mt] += lsum;
            // B-frag: keys q*8..q*8+7 in order — pure in-lane packs, no shuffles
            union { unsigned u[4]; short8 s8; } pu;
            pu.u[0] = pk2bf(p0[0], p0[1]);
            pu.u[1] = pk2bf(p0[2], p0[3]);
            pu.u[2] = pk2bf(p1[0], p1[1]);
            pu.u[3] = pk2bf(p1[2], p1[3]);
            short8 pb = pu.s8;
            O[mt][0] = __builtin_amdgcn_mfma_f32_16x16x32_bf16(vf0, pb, O[mt][0], 0, 0, 0);
            O[mt][1] = __builtin_amdgcn_mfma_f32_16x16x32_bf16(vf1, pb, O[mt][1], 0, 0, 0);
        }
    }

#pragma unroll
    for (int mt = 0; mt < 4; mt++) {
        float v = lpv[mt];
        v += __shfl_xor(v, 16);
        v += __shfl_xor(v, 32);
        lpv[mt] = 1.0f / v;
    }
#pragma unroll
    for (int mt = 0; mt < 4; mt++) {
        float linv = lpv[mt];
        int query = w * 64 + mt * 16 + r;
        short* dst = att + ((size_t)b_ * 256 + query) * 192 + h * 32 + q * 4;
#pragma unroll
        for (int nt = 0; nt < 2; nt++) {
            short4v pv;
#pragma unroll
            for (int reg = 0; reg < 4; reg++) pv[reg] = f2bf(O[mt][nt][reg] * linv);
            *(short4v*)(dst + nt * 16) = pv;
        }
    }
}

// ---------------------------------------------------------------- K4: out-proj via bf16 MFMA (swapped operands) + LN + roll-scatter + residual
__global__ __launch_bounds__(256) void proj_mfma_k(const short* __restrict__ att,
                                                   const short* __restrict__ wpp,
                                                   const float* __restrict__ proj_b,
                                                   const float* __restrict__ x,
                                                   const float* __restrict__ g1,
                                                   const float* __restrict__ b1n,
                                                   float* __restrict__ out,
                                                   short* __restrict__ xmb) {
    __shared__ float ps[32][4], pss[32][4];
    __shared__ float mean_s[32], inv_s[32];
    int tid = threadIdx.x, lane = tid & 63, w = tid >> 6;
    int r = lane & 15, q = lane >> 4;
    int b_ = blockIdx.x >> 3, n0 = (blockIdx.x & 7) << 5;

    short8 af[2][6];
#pragma unroll
    for (int m = 0; m < 2; m++) {
        const short* src = att + ((size_t)b_ * 256 + n0 + m * 16 + r) * 192 + q * 8;
#pragma unroll
        for (int kt = 0; kt < 6; kt++)
            af[m][kt] = *(const short8*)(src + kt * 32);
    }
    f32x4 acc[3][2];
#pragma unroll
    for (int ntl = 0; ntl < 3; ntl++) {
        int nt = w * 3 + ntl;
        f32x4 binit = *(const f32x4*)(proj_b + nt * 16 + q * 4);
        short8 bfr[6];
#pragma unroll
        for (int kt = 0; kt < 6; kt++)
            bfr[kt] = ((const short8*)wpp)[(size_t)(nt * 6 + kt) * 64 + lane];
        f32x4 a0 = binit, a1 = binit;
#pragma unroll
        for (int kt = 0; kt < 6; kt++) {
            a0 = __builtin_amdgcn_mfma_f32_16x16x32_bf16(bfr[kt], af[0][kt], a0, 0, 0, 0);
            a1 = __builtin_amdgcn_mfma_f32_16x16x32_bf16(bfr[kt], af[1][kt], a1, 0, 0, 0);
        }
        acc[ntl][0] = a0;
        acc[ntl][1] = a1;
    }
    float s0 = 0.f, ss0 = 0.f, s1 = 0.f, ss1 = 0.f;
#pragma unroll
    for (int ntl = 0; ntl < 3; ntl++)
#pragma unroll
        for (int reg = 0; reg < 4; reg++) {
            float z0 = acc[ntl][0][reg], z1 = acc[ntl][1][reg];
            s0 += z0; ss0 += z0 * z0;
            s1 += z1; ss1 += z1 * z1;
        }
    s0 += __shfl_xor(s0, 16); ss0 += __shfl_xor(ss0, 16);
    s0 += __shfl_xor(s0, 32); ss0 += __shfl_xor(ss0, 32);
    s1 += __shfl_xor(s1, 16); ss1 += __shfl_xor(ss1, 16);
    s1 += __shfl_xor(s1, 32); ss1 += __shfl_xor(ss1, 32);
    if (q == 0) {
        ps[r][w] = s0;  pss[r][w] = ss0;
        ps[16 + r][w] = s1;  pss[16 + r][w] = ss1;
    }
    __syncthreads();
    if (tid < 32) {
        float sm = ps[tid][0] + ps[tid][1] + ps[tid][2] + ps[tid][3];
        float sq = pss[tid][0] + pss[tid][1] + pss[tid][2] + pss[tid][3];
        float mean = sm * (1.0f / 192.0f);
        float var = sq * (1.0f / 192.0f) - mean * mean;
        mean_s[tid] = mean;
        inv_s[tid] = 1.0f / sqrtf(var + 1e-5f);
    }
    __syncthreads();
    int b = b_ >> 7, win = b_ & 127;
    int wt = win >> 6, wh = (win >> 3) & 7, ww = win & 7;
#pragma unroll
    for (int mh = 0; mh < 2; mh++) {
        int token = mh * 16 + r;
        int n = n0 + token;
        int t0 = ((wt * 4 + (n >> 6)) + 2) & 7;
        int h0 = ((wh * 8 + ((n >> 3) & 7)) + 4) & 63;
        int w0 = ((ww * 8 + (n & 7)) + 4) & 63;
        size_t gb = ((size_t)((b * 8 + t0) * 64 + h0) * 64 + w0) * 192;
        float mean = mean_s[token], inv = inv_s[token];
#pragma unroll
        for (int ntl = 0; ntl < 3; ntl++) {
            int ch = (w * 3 + ntl) * 16 + q * 4;
            f32x4 zv = acc[ntl][mh];
            f32x4 gv = *(const f32x4*)(g1 + ch);
            f32x4 bv = *(const f32x4*)(b1n + ch);
            f32x4 xv = *(const f32x4*)(x + gb + ch);
            f32x4 o;
            short4v xm;
#pragma unroll
            for (int j = 0; j < 4; j++) {
                o[j] = xv[j] + (zv[j] - mean) * inv * gv[j] + bv[j];
                xm[j] = f2bf(o[j]);
            }
            *(f32x4*)(out + gb + ch) = o;
            *(short4v*)(xmb + gb + ch) = xm;
        }
    }
}

// ---------------------------------------------------------------- K5: MLP — R9 form (Xs staging), PERMANENT
// R3+R10 both proved: mlp's live state (~90 regs) needs the 65-128 VGPR band ->
// 4 waves/SIMD is its hard ceiling; VGPR<=64 attempts spill (+400MB HBM, 2x).
// The Xs staging loop anchors the allocator at 56 VGPR / no spill.
#define XSTR 200
#define H2STR 264
__global__ __launch_bounds__(512, 4) void mlp_mfma_k(const short* __restrict__ xmb,
                                                     const short* __restrict__ w1p,
                                                     const short* __restrict__ w2p,
                                                     const float* __restrict__ fc1_b,
                                                     const float* __restrict__ fc2_b,
                                                     const float* __restrict__ g2,
                                                     const float* __restrict__ b2,
                                                     float* __restrict__ out) {
    __shared__ short Xs[64 * XSTR];   // 25600 B
    __shared__ short Hs[64 * H2STR];  // 33792 B
    __shared__ float ps[64][4], pss[64][4];
    __shared__ float mean_s[64], inv_s[64];
    int tid = threadIdx.x;
    int lane = tid & 63, w = tid >> 6;
    int r = lane & 15, q = lane >> 4;
    size_t tok0 = (size_t)blockIdx.x * 64;

    for (int i = tid; i < 1536; i += 512) {
        int token = i / 24, ch8 = (i - token * 24) * 8;
        short8 v = *(const short8*)(xmb + (tok0 + token) * 192 + ch8);
        *(short8*)&Xs[token * XSTR + ch8] = v;
    }
    __syncthreads();

    int mg = w >> 2;
    int ng = w & 3;
    f32x4 acc2[6];
#pragma unroll
    for (int i = 0; i < 6; i++) acc2[i] = (f32x4){0.f, 0.f, 0.f, 0.f};

    for (int c = 0; c < 3; c++) {
        {
            int ntg0 = c * 16 + 2 * w;
            f32x4 a[2][4];
#pragma unroll
            for (int ntl = 0; ntl < 2; ntl++) {
                f32x4 binit = *(const f32x4*)(fc1_b + (ntg0 + ntl) * 16 + q * 4);
#pragma unroll
                for (int m = 0; m < 4; m++) a[ntl][m] = binit;
            }
#pragma unroll
            for (int kt = 0; kt < 6; kt++) {
                short8 w0 = ((const short8*)w1p)[(size_t)((ntg0) * 6 + kt) * 64 + lane];
                short8 w1f = ((const short8*)w1p)[(size_t)((ntg0 + 1) * 6 + kt) * 64 + lane];
                short8 xb[4];
#pragma unroll
                for (int m = 0; m < 4; m++)
                    xb[m] = *(const short8*)&Xs[(m * 16 + r) * XSTR + kt * 32 + q * 8];
#pragma unroll
                for (int m = 0; m < 4; m++) {
                    a[0][m] = __builtin_amdgcn_mfma_f32_16x16x32_bf16(w0, xb[m], a[0][m], 0, 0, 0);
                    a[1][m] = __builtin_amdgcn_mfma_f32_16x16x32_bf16(w1f, xb[m], a[1][m], 0, 0, 0);
                }
            }
#pragma unroll
            for (int ntl = 0; ntl < 2; ntl++) {
                int hcol = (2 * w + ntl) * 16 + q * 4;
#pragma unroll
                for (int m = 0; m < 4; m++) {
                    short4v p;
#pragma unroll
                    for (int reg = 0; reg < 4; reg++) p[reg] = f2bf(gelu_fast(a[ntl][m][reg]));
                    *(short4v*)&Hs[(m * 16 + r) * H2STR + hcol] = p;
                }
            }
        }
        __syncthreads();

#pragma unroll
        for (int kk = 0; kk < 8; kk++) {
            short8 hb0 = *(const short8*)&Hs[((mg * 2) * 16 + r) * H2STR + kk * 32 + q * 8];
            short8 hb1 = *(const short8*)&Hs[((mg * 2 + 1) * 16 + r) * H2STR + kk * 32 + q * 8];
            int kkg = c * 8 + kk;
#pragma unroll
            for (int n = 0; n < 3; n++) {
                int ntz = ng * 3 + n;
                short8 wf = ((const short8*)w2p)[(size_t)(ntz * 24 + kkg) * 64 + lane];
                acc2[n * 2 + 0] = __builtin_amdgcn_mfma_f32_16x16x32_bf16(wf, hb0, acc2[n * 2 + 0], 0, 0, 0);
                acc2[n * 2 + 1] = __builtin_amdgcn_mfma_f32_16x16x32_bf16(wf, hb1, acc2[n * 2 + 1], 0, 0, 0);
            }
        }
        __syncthreads();
    }

    float s0 = 0.f, ss0 = 0.f, s1 = 0.f, ss1 = 0.f;
#pragma unroll
    for (int n = 0; n < 3; n++) {
        f32x4 b4 = *(const f32x4*)(fc2_b + (ng * 3 + n) * 16 + q * 4);
        f32x4 z0 = acc2[n * 2 + 0] + b4;
        f32x4 z1 = acc2[n * 2 + 1] + b4;
        acc2[n * 2 + 0] = z0;
        acc2[n * 2 + 1] = z1;
#pragma unroll
        for (int reg = 0; reg < 4; reg++) {
            s0 += z0[reg]; ss0 += z0[reg] * z0[reg];
            s1 += z1[reg]; ss1 += z1[reg] * z1[reg];
        }
    }
    s0 += __shfl_xor(s0, 16); ss0 += __shfl_xor(ss0, 16);
    s0 += __shfl_xor(s0, 32); ss0 += __shfl_xor(ss0, 32);
    s1 += __shfl_xor(s1, 16); ss1 += __shfl_xor(ss1, 16);
    s1 += __shfl_xor(s1, 32); ss1 += __shfl_xor(ss1, 32);
    if (q == 0) {
        int t0 = mg * 32 + r;
        ps[t0][ng] = s0;  pss[t0][ng] = ss0;
        ps[t0 + 16][ng] = s1;  pss[t0 + 16][ng] = ss1;
    }
    __syncthreads();
    if (tid < 64) {
        float sm = ps[tid][0] + ps[tid][1] + ps[tid][2] + ps[tid][3];
        float sq = pss[tid][0] + pss[tid][1] + pss[tid][2] + pss[tid][3];
        float mean = sm * (1.0f / 192.0f);
        float var = sq * (1.0f / 192.0f) - mean * mean;
        mean_s[tid] = mean;
        inv_s[tid] = 1.0f / sqrtf(var + 1e-5f);
    }
    __syncthreads();
#pragma unroll
    for (int n = 0; n < 3; n++) {
        int ntz = ng * 3 + n;
        f32x4 g4 = *(const f32x4*)(g2 + ntz * 16 + q * 4);
        f32x4 bb4 = *(const f32x4*)(b2 + ntz * 16 + q * 4);
#pragma unroll
        for (int mh = 0; mh < 2; mh++) {
            int token = mg * 32 + mh * 16 + r;
            float mean = mean_s[token], inv = inv_s[token];
            size_t gi = (tok0 + token) * 192 + ntz * 16 + q * 4;
            f32x4 o = *(const f32x4*)(out + gi);
            f32x4 z = acc2[n * 2 + mh];
            f32x4 res;
#pragma unroll
            for (int reg = 0; reg < 4; reg++)
                res[reg] = o[reg] + (z[reg] - mean) * inv * g4[reg] + bb4[reg];
            *(f32x4*)(out + gi) = res;
        }
    }
}

// ---------------------------------------------------------------- launch
extern "C" void kernel_launch(void* const* d_in, const int* in_sizes, int n_in,
                              void* d_out, int out_size, void* d_ws, size_t ws_size,
                              hipStream_t stream) {
    const float* x           = (const float*)d_in[0];
    const float* qkv_w       = (const float*)d_in[1];
    const float* qkv_b       = (const float*)d_in[2];
    const float* proj_w      = (const float*)d_in[3];
    const float* proj_b      = (const float*)d_in[4];
    const float* cpb_w1      = (const float*)d_in[5];
    const float* cpb_b1      = (const float*)d_in[6];
    const float* cpb_w2      = (const float*)d_in[7];
    const float* logit_scale = (const float*)d_in[8];
    const float* norm1_g     = (const float*)d_in[9];
    const float* norm1_b     = (const float*)d_in[10];
    const float* norm2_g     = (const float*)d_in[11];
    const float* norm2_b     = (const float*)d_in[12];
    const float* fc1_w       = (const float*)d_in[13];
    const float* fc1_b       = (const float*)d_in[14];
    const float* fc2_w       = (const float*)d_in[15];
    const float* fc2_b       = (const float*)d_in[16];
    float* out = (float*)d_out;

    float* ws = (float*)d_ws;
    const size_t QKVE = (size_t)256 * 6 * 256 * 32;   // 12,582,912 elems
    short* att    = (short*)ws;                       // bf16, region kept fp32-sized
    short* biasQK = (short*)(ws + QKVE);              // fp16, 393,216 shorts
    float* tbl6   = ws + QKVE + (size_t)6 * 256 * 256;  // 9,450 fp32
    short* w1pack = (short*)(tbl6 + 9472);
    short* w2pack = w1pack + (size_t)768 * 192;
    short* wqpack = w2pack + (size_t)192 * 768;
    short* wppack = wqpack + (size_t)576 * 192;
    short* qbf    = wppack + (size_t)192 * 192;       // bf16, 12,582,912 each
    short* kbf    = qbf + QKVE;
    short* vtb    = kbf + QKVE;
    short* xmb    = vtb + QKVE;                       // bf16 x_mid, raster order

    hipLaunchKernelGGL(setup_k, dim3(2439), dim3(64), 0, stream,
                       fc1_w, w1pack, fc2_w, w2pack, qkv_w, wqpack, proj_w, wppack,
                       cpb_w1, cpb_b1, cpb_w2, tbl6);
    hipLaunchKernelGGL(bias_k, dim3(1536), dim3(256), 0, stream, tbl6, biasQK);
    hipLaunchKernelGGL(qkv_mfma_k, dim3(2048), dim3(256), 0, stream, x, wqpack, qkv_b, qbf, kbf, vtb);
    hipLaunchKernelGGL(attn_mfma_k, dim3(1536), dim3(256), 0, stream, qbf, kbf, vtb, biasQK, logit_scale, att);
    hipLaunchKernelGGL(proj_mfma_k, dim3(2048), dim3(256), 0, stream, att, wppack, proj_b, x, norm1_g, norm1_b, out, xmb);
    hipLaunchKernelGGL(mlp_mfma_k, dim3(1024), dim3(512), 0, stream, xmb, w1pack, w2pack,
                       fc1_b, fc2_b, norm2_g, norm2_b, out);
}